// Round 6
// baseline (266.972 us; speedup 1.0000x reference)
//
#include <hip/hip_runtime.h>
#include <hip/hip_bf16.h>

#define B_    8
#define N_    1024
#define F_    128
#define G_    64
#define EC    2
#define NHD   4
#define NE    16384
#define L0_   256
#define ALPHA_ 0.5f
#define EPS_   1e-5f
#define SLOPE_ 0.01f
#define ROWS  (B_*N_)      // 8192
#define C1    (NHD*EC*G_)  // 512

__device__ __forceinline__ float ldv(const float* p, size_t i) { return p[i]; }
__device__ __forceinline__ float ldv(const __hip_bfloat16* p, size_t i) {
  unsigned short u = *(const unsigned short*)&p[i];
  return __uint_as_float((unsigned)u << 16);
}
__device__ __forceinline__ void ld4(const float* p, float& a, float& b, float& c, float& d) {
  float4 v = *(const float4*)p; a = v.x; b = v.y; c = v.z; d = v.w;
}
__device__ __forceinline__ void ld4(const __hip_bfloat16* p, float& a, float& b, float& c, float& d) {
  ushort4 v = *(const ushort4*)p;
  a = __uint_as_float((unsigned)v.x << 16); b = __uint_as_float((unsigned)v.y << 16);
  c = __uint_as_float((unsigned)v.z << 16); d = __uint_as_float((unsigned)v.w << 16);
}

__device__ __forceinline__ float wmaxf(float v) {
#pragma unroll
  for (int o = 32; o; o >>= 1) v = fmaxf(v, __shfl_xor(v, o, 64));
  return v;
}
__device__ __forceinline__ float wsumf(float v) {
#pragma unroll
  for (int o = 32; o; o >>= 1) v += __shfl_xor(v, o, 64);
  return v;
}

// ---- dtype detector (proven round 2 — do not change logic) ----------------
__global__ void k_detect(const unsigned short* Xu, int* flag) {
  int idx = blockIdx.x * 256 + threadIdx.x;
  unsigned short u = Xu[idx];
  if ((u & 0x7F80u) == 0x7F80u) atomicOr(flag, 1);
}

// ---- q/v projections ------------------------------------------------------
template <typename T>
__device__ __forceinline__ void proj_qv_body(const T* X, const T* Wq, const T* Wv,
                                             float* q, float* v) {
  int tid = threadIdx.x, lane = tid & 63, w = tid >> 6;
  int r = blockIdx.x * 4 + w;
  int n = r & (N_ - 1); int beh = r >> 10; int be = beh >> 2, h = beh & 3;
  int b = be >> 1, e = be & 1;
  const T* xr = X + ((size_t)(b * N_ + n)) * F_;
  const T* wq = Wq + (e * NHD + h) * F_;
  const T* wv = Wv + (e * NHD + h) * F_;
  float x0 = ldv(xr, lane), x1 = ldv(xr, lane + 64);
  float aq = x0 * ldv(wq, lane) + x1 * ldv(wq, lane + 64);
  float av = x0 * ldv(wv, lane) + x1 * ldv(wv, lane + 64);
  aq = wsumf(aq); av = wsumf(av);
  if (lane == 0) { q[r] = aq; v[r] = av; }
}
__global__ void k_proj_qv(const void* X, const void* Wq, const void* Wv,
                          float* q, float* v, const int* flag) {
  if (*flag) proj_qv_body<float>((const float*)X, (const float*)Wq, (const float*)Wv, q, v);
  else       proj_qv_body<__hip_bfloat16>((const __hip_bfloat16*)X, (const __hip_bfloat16*)Wq,
                                          (const __hip_bfloat16*)Wv, q, v);
}

// ---- Wh projection GEMM + fused column-sum S ------------------------------
template <typename TW>
__device__ __forceinline__ void wh_body(const TW* X, const TW* Wsrc, float* Wh, float* S,
                                        float* smem) {
  constexpr int KDIM = 128, KT = 64, NCOL = 64, RT = 64, RTP = 68, NP = 68;
  float* As = smem;                 // KT*RTP
  float* Ws = smem + KT * RTP;      // KT*NP
  int tid = threadIdx.x, tx = tid & 15, ty = tid >> 4;
  int row0 = blockIdx.x * RT; int eh = blockIdx.y;
  const TW* Wp = Wsrc + (size_t)eh * KDIM * NCOL;
  float acc[4][4] = {};
  for (int k0 = 0; k0 < KDIM; k0 += KT) {
    for (int t = tid; t < RT * KT / 4; t += 256) {
      int rr = t >> 4, k4 = t & 15;
      float a0, a1, a2, a3;
      ld4(X + (size_t)(row0 + rr) * KDIM + k0 + k4 * 4, a0, a1, a2, a3);
      As[(k4 * 4 + 0) * RTP + rr] = a0; As[(k4 * 4 + 1) * RTP + rr] = a1;
      As[(k4 * 4 + 2) * RTP + rr] = a2; As[(k4 * 4 + 3) * RTP + rr] = a3;
    }
    for (int t = tid; t < KT * NCOL / 4; t += 256) {
      int col4 = t & 15, k = t >> 4;
      float w0, w1, w2, w3;
      ld4(Wp + (size_t)(k0 + k) * NCOL + col4 * 4, w0, w1, w2, w3);
      *(float4*)(Ws + k * NP + col4 * 4) = make_float4(w0, w1, w2, w3);
    }
    __syncthreads();
    // depth-4 register pipeline over k
    float4 ap[4], wp[4];
#pragma unroll
    for (int j = 0; j < 4; ++j) {
      ap[j] = *(const float4*)(As + j * RTP + ty * 4);
      wp[j] = *(const float4*)(Ws + j * NP + tx * 4);
    }
#pragma unroll 8
    for (int k = 0; k < KT; ++k) {
      float4 av = ap[0], wv = wp[0];
      ap[0] = ap[1]; ap[1] = ap[2]; ap[2] = ap[3];
      wp[0] = wp[1]; wp[1] = wp[2]; wp[2] = wp[3];
      int kp = (k + 4 < KT) ? (k + 4) : (KT - 1);
      ap[3] = *(const float4*)(As + kp * RTP + ty * 4);
      wp[3] = *(const float4*)(Ws + kp * NP + tx * 4);
      acc[0][0] += av.x * wv.x; acc[0][1] += av.x * wv.y; acc[0][2] += av.x * wv.z; acc[0][3] += av.x * wv.w;
      acc[1][0] += av.y * wv.x; acc[1][1] += av.y * wv.y; acc[1][2] += av.y * wv.z; acc[1][3] += av.y * wv.w;
      acc[2][0] += av.z * wv.x; acc[2][1] += av.z * wv.y; acc[2][2] += av.z * wv.z; acc[2][3] += av.z * wv.w;
      acc[3][0] += av.w * wv.x; acc[3][1] += av.w * wv.y; acc[3][2] += av.w * wv.z; acc[3][3] += av.w * wv.w;
    }
    __syncthreads();
  }
  int b = row0 >> 10;           // 64-row tiles never cross a batch boundary
  float colS[4] = {};
#pragma unroll
  for (int i = 0; i < 4; ++i) {
    int r = row0 + ty * 4 + i; int n = r & (N_ - 1);
    size_t base = ((size_t)(b * 8 + eh) * N_ + n) * G_ + tx * 4;
#pragma unroll
    for (int j = 0; j < 4; ++j) { Wh[base + j] = acc[i][j]; colS[j] += acc[i][j]; }
  }
  float* red = smem;            // 16*64 floats; safe after last sync
#pragma unroll
  for (int j = 0; j < 4; ++j) red[ty * 64 + tx * 4 + j] = colS[j];
  __syncthreads();
  if (tid < 64) {
    float s = 0.f;
#pragma unroll
    for (int t = 0; t < 16; ++t) s += red[t * 64 + tid];
    atomicAdd(&S[(size_t)(b * 8 + eh) * G_ + tid], s);
  }
}
__global__ __launch_bounds__(256) void k_whg(const void* X, const void* Ws, float* Wh,
                                             float* S, const int* flag) {
  __shared__ __align__(16) float smem[64 * 68 + 64 * 68];
  if (*flag) wh_body<float>((const float*)X, (const float*)Ws, Wh, S, smem);
  else       wh_body<__hip_bfloat16>((const __hip_bfloat16*)X, (const __hip_bfloat16*)Ws, Wh, S, smem);
}

// ---- adjacency: direct fixed-capacity buckets -----------------------------
__global__ void k_scatter2(const int* A, int* fill, int* colbuf) {
  int idx = blockIdx.x * 256 + threadIdx.x;    // 16*NE
  int be = idx >> 14, i = idx & (NE - 1);
  int row = A[(size_t)(be * 2) * NE + i];
  int col = A[(size_t)(be * 2 + 1) * NE + i];
  int p = atomicAdd(&fill[be * N_ + row], 1);
  if (p < 64) colbuf[((size_t)(be * N_ + row)) * 64 + p] = col;
}

// ---- sparse attention: one block per (be,n); wave0 dedups once ------------
__global__ __launch_bounds__(256) void k_attn2(const float* q, const float* v, const float* Wh,
                                               const float* S, const int* fill,
                                               const int* colbuf, float* Hcat) {
  __shared__ int s_col[64];
  __shared__ int s_cnt[64];
  __shared__ int s_ld;
  __shared__ float s_w[4][64];
  int tid = threadIdx.x, lane = tid & 63, h = tid >> 6;
  int be = blockIdx.x >> 10, n = blockIdx.x & (N_ - 1);
  int b = be >> 1, e = be & 1;
  if (h == 0) {
    int L = fill[be * N_ + n];
    int Lc = (L > 64) ? 64 : L;
    int myc = (lane < Lc) ? colbuf[((size_t)(be * N_ + n)) * 64 + lane] : -1;
    int cct = 0, firstk = 64;
    for (int k = 0; k < Lc; ++k) {
      int ck = __shfl(myc, k, 64);
      if (myc >= 0 && ck == myc) { cct++; if (k < firstk) firstk = k; }
    }
    bool act = (lane < Lc) && (firstk == lane);
    unsigned long long mask = __ballot(act);
    int pos = __popcll(mask & ((1ull << lane) - 1ull));
    if (act) { s_col[pos] = myc; s_cnt[pos] = cct; }
    if (lane == 0) s_ld = __popcll(mask);
  }
  __syncthreads();
  int Ld = s_ld;
  int beh = (be << 2) | h;
  float qn = q[beh * N_ + n];
  float sc = -1e30f;
  if (lane < Ld) {
    float t = qn * v[beh * N_ + s_col[lane]] * (float)s_cnt[lane];
    sc = (t >= 0.f) ? t : SLOPE_ * t;
  }
  float M = fmaxf(0.f, wmaxf(sc));
  float Ej = (lane < Ld) ? expf(sc - M) : 0.f;
  float sumE = wsumf(Ej);
  float em = expf(-M);
  float Z = (float)(N_ - Ld) * em + sumE;
  s_w[h][lane] = (lane < Ld) ? (Ej - em) / Z : 0.f;
  float acc = (em / Z) * S[(size_t)beh * G_ + lane];
  const float* WhB = Wh + (size_t)beh * N_ * G_;
  // chunk-of-8 prefetch: 8 independent global loads in flight per vmcnt wait
  for (int k0 = 0; k0 < Ld; k0 += 8) {
    float xs[8];
#pragma unroll
    for (int j = 0; j < 8; ++j) {
      int kk = k0 + j; int idx = (kk < Ld) ? kk : 0;
      xs[j] = WhB[(size_t)s_col[idx] * G_ + lane];
    }
#pragma unroll
    for (int j = 0; j < 8; ++j) {
      int kk = k0 + j;
      if (kk < Ld) acc += s_w[h][kk] * xs[j];
    }
  }
  Hcat[((size_t)(b * N_ + n)) * C1 + h * (EC * G_) + e * G_ + lane] = acc;
}

// ---- generic 32x128 tiled GEMM with fused BN-stats epilogue ---------------
template <int KDIM, int KT, int MODEA, int EP, typename TW>
__device__ __forceinline__ void gemm128_body(
    const float* __restrict__ Araw, const TW* __restrict__ W, const TW* __restrict__ Xsrc,
    const float* __restrict__ Res,
    const float* sAsum, const float* sAssq, const float* sRsum, const float* sRssq,
    float* oSum, float* oSsq,
    float* __restrict__ C, int cstride, float* smem) {
  constexpr int NCOL = 128, RT = 32, RTP = 36, NP = 132;
  float* As = smem;               // KT*RTP
  float* Ws = smem + KT * RTP;    // KT*NP
  int tid = threadIdx.x, tx = tid & 31, ty = tid >> 5;
  int row0 = blockIdx.x * RT;
  int col0 = blockIdx.y * NCOL;
  float acc[4][4] = {};
  for (int k0 = 0; k0 < KDIM; k0 += KT) {
    for (int t = tid; t < RT * KT / 4; t += 256) {
      int rr = t / (KT / 4), k4 = t % (KT / 4);
      float4 val = *(const float4*)(Araw + (size_t)(row0 + rr) * KDIM + k0 + k4 * 4);
      if (MODEA) {
        float* vp = &val.x;
#pragma unroll
        for (int j = 0; j < 4; ++j) {
          int c = k0 + k4 * 4 + j;
          float mean = sAsum[c] * (1.f / ROWS);
          float var = sAssq[c] * (1.f / ROWS) - mean * mean;
          float y = (vp[j] - mean) * rsqrtf(var + EPS_);
          if (MODEA == 2) y = (y > 0.f) ? y : (expf(y) - 1.f);
          vp[j] = y;
        }
      }
      As[(k4 * 4 + 0) * RTP + rr] = val.x; As[(k4 * 4 + 1) * RTP + rr] = val.y;
      As[(k4 * 4 + 2) * RTP + rr] = val.z; As[(k4 * 4 + 3) * RTP + rr] = val.w;
    }
    for (int t = tid; t < NCOL * KT / 4; t += 256) {
      int col = t & (NCOL - 1), k4 = t >> 7;
      float w0, w1, w2, w3;
      ld4(W + (size_t)(col0 + col) * KDIM + k0 + k4 * 4, w0, w1, w2, w3);
      Ws[(k4 * 4 + 0) * NP + col] = w0; Ws[(k4 * 4 + 1) * NP + col] = w1;
      Ws[(k4 * 4 + 2) * NP + col] = w2; Ws[(k4 * 4 + 3) * NP + col] = w3;
    }
    __syncthreads();
    // depth-4 register pipeline over k
    float4 ap[4], wp[4];
#pragma unroll
    for (int j = 0; j < 4; ++j) {
      ap[j] = *(const float4*)(As + j * RTP + ty * 4);
      wp[j] = *(const float4*)(Ws + j * NP + tx * 4);
    }
#pragma unroll 8
    for (int k = 0; k < KT; ++k) {
      float4 av = ap[0], wv = wp[0];
      ap[0] = ap[1]; ap[1] = ap[2]; ap[2] = ap[3];
      wp[0] = wp[1]; wp[1] = wp[2]; wp[2] = wp[3];
      int kp = (k + 4 < KT) ? (k + 4) : (KT - 1);
      ap[3] = *(const float4*)(As + kp * RTP + ty * 4);
      wp[3] = *(const float4*)(Ws + kp * NP + tx * 4);
      acc[0][0] += av.x * wv.x; acc[0][1] += av.x * wv.y; acc[0][2] += av.x * wv.z; acc[0][3] += av.x * wv.w;
      acc[1][0] += av.y * wv.x; acc[1][1] += av.y * wv.y; acc[1][2] += av.y * wv.z; acc[1][3] += av.y * wv.w;
      acc[2][0] += av.z * wv.x; acc[2][1] += av.z * wv.y; acc[2][2] += av.z * wv.z; acc[2][3] += av.z * wv.w;
      acc[3][0] += av.w * wv.x; acc[3][1] += av.w * wv.y; acc[3][2] += av.w * wv.z; acc[3][3] += av.w * wv.w;
    }
    __syncthreads();
  }
  float colS[4] = {}, colS2[4] = {};
#pragma unroll
  for (int i = 0; i < 4; ++i) {
    int r = row0 + ty * 4 + i;
#pragma unroll
    for (int j = 0; j < 4; ++j) {
      int c = col0 + tx * 4 + j;
      float o = acc[i][j];
      if (EP == 1) {
        o = fmaxf(o, 0.f);
        o = (1.f - ALPHA_) * o + ALPHA_ * ldv(Xsrc, (size_t)r * F_ + c);
      } else if (EP == 2) {
        float x = Res[(size_t)r * 128 + c];
        float mean = sRsum[c] * (1.f / ROWS);
        float var = sRssq[c] * (1.f / ROWS) - mean * mean;
        o += (x - mean) * rsqrtf(var + EPS_);
      }
      C[(size_t)r * cstride + c] = o;
      colS[j] += o; colS2[j] += o * o;
    }
  }
  float* red = smem;              // 8*128*2 = 2048 floats; safe after last sync
#pragma unroll
  for (int j = 0; j < 4; ++j) {
    red[ty * 256 + (tx * 4 + j) * 2 + 0] = colS[j];
    red[ty * 256 + (tx * 4 + j) * 2 + 1] = colS2[j];
  }
  __syncthreads();
  if (tid < 128) {
    float s = 0.f, s2 = 0.f;
#pragma unroll
    for (int t = 0; t < 8; ++t) { s += red[t * 256 + tid * 2]; s2 += red[t * 256 + tid * 2 + 1]; }
    atomicAdd(&oSum[col0 + tid], s); atomicAdd(&oSsq[col0 + tid], s2);
  }
}

#define GEMM_SMEM (64 * 36 + 64 * 132)

__global__ __launch_bounds__(256) void k_mm1g(const float* A, const void* W, const void* X,
                                              float* C, float* oSum, float* oSsq,
                                              const int* flag) {
  __shared__ __align__(16) float smem[GEMM_SMEM];
  if (*flag)
    gemm128_body<512, 64, 0, 1, float>(A, (const float*)W, (const float*)X, nullptr,
                                       nullptr, nullptr, nullptr, nullptr, oSum, oSsq,
                                       C, 128, smem);
  else
    gemm128_body<512, 64, 0, 1, __hip_bfloat16>(A, (const __hip_bfloat16*)W,
                                                (const __hip_bfloat16*)X, nullptr,
                                                nullptr, nullptr, nullptr, nullptr, oSum, oSsq,
                                                C, 128, smem);
}
__global__ __launch_bounds__(256) void k_lin0g(const float* A, const void* W, float* C,
                                               const float* s1sum, const float* s1ssq,
                                               float* oSum, float* oSsq, const int* flag) {
  __shared__ __align__(16) float smem[GEMM_SMEM];
  if (*flag)
    gemm128_body<128, 64, 1, 0, float>(A, (const float*)W, nullptr, nullptr,
                                       s1sum, s1ssq, nullptr, nullptr, oSum, oSsq,
                                       C, 256, smem);
  else
    gemm128_body<128, 64, 1, 0, __hip_bfloat16>(A, (const __hip_bfloat16*)W, nullptr, nullptr,
                                                s1sum, s1ssq, nullptr, nullptr, oSum, oSsq,
                                                C, 256, smem);
}
__global__ __launch_bounds__(256) void k_lin1g(const float* A, const void* W, const float* Res,
                                               float* C, const float* s2sum, const float* s2ssq,
                                               const float* s1sum, const float* s1ssq,
                                               float* oSum, float* oSsq, const int* flag) {
  __shared__ __align__(16) float smem[GEMM_SMEM];
  if (*flag)
    gemm128_body<256, 64, 2, 2, float>(A, (const float*)W, nullptr, Res,
                                       s2sum, s2ssq, s1sum, s1ssq, oSum, oSsq,
                                       C, 128, smem);
  else
    gemm128_body<256, 64, 2, 2, __hip_bfloat16>(A, (const __hip_bfloat16*)W, nullptr, Res,
                                                s2sum, s2ssq, s1sum, s1ssq, oSum, oSsq,
                                                C, 128, smem);
}

__global__ void k_norm_out(const float* in, void* out, const float* sum, const float* ssq,
                           const int* flag) {
  int idx = blockIdx.x * 256 + threadIdx.x; int c = idx & (F_ - 1);
  float mean = sum[c] * (1.f / ROWS);
  float var = ssq[c] * (1.f / ROWS) - mean * mean;
  float y = (in[idx] - mean) * rsqrtf(var + EPS_);
  if (*flag) ((float*)out)[idx] = y;
  else       ((__hip_bfloat16*)out)[idx] = __float2bfloat16(y);
}

// ---------------------------------------------------------------------------
extern "C" void kernel_launch(void* const* d_in, const int* in_sizes, int n_in,
                              void* d_out, int out_size, void* d_ws, size_t ws_size,
                              hipStream_t stream) {
  const int* A    = (const int*)d_in[0];
  const void* X   = d_in[1];
  const void* Ws  = d_in[2];
  const void* Wq  = d_in[3];
  const void* Wv  = d_in[4];
  const void* We1 = d_in[5];
  const void* Wl0 = d_in[6];
  const void* Wl1 = d_in[7];

  char* ws = (char*)d_ws;
  size_t off = 0;
  auto alloc = [&](size_t bytes) { size_t o = off; off += (bytes + 255) & ~(size_t)255; return o; };
  size_t o_fill   = alloc(16 * N_ * 4);            // zeroed
  size_t o_stats  = alloc(1024 * 4);               // zeroed
  size_t o_flag   = alloc(256);                    // zeroed
  size_t o_S      = alloc((size_t)64 * G_ * 4);    // zeroed (atomic accum)
  size_t zero_bytes = off;
  size_t o_colbuf = alloc((size_t)16 * N_ * 64 * 4);    // 4 MiB
  size_t o_q      = alloc((size_t)64 * N_ * 4);
  size_t o_v      = alloc((size_t)64 * N_ * 4);
  size_t o_Wh     = alloc((size_t)64 * N_ * G_ * 4);    // 16 MiB
  size_t o_Hcat   = alloc((size_t)ROWS * C1 * 4);       // 16 MiB
  size_t o_T4     = alloc((size_t)ROWS * F_ * 4);
  size_t o_T6     = alloc((size_t)ROWS * F_ * 4);
  size_t o_Z0     = alloc((size_t)ROWS * L0_ * 4);

  int*   fill   = (int*)(ws + o_fill);
  float* stats  = (float*)(ws + o_stats);
  int*   flag   = (int*)(ws + o_flag);
  float* S      = (float*)(ws + o_S);
  int*   colbuf = (int*)(ws + o_colbuf);
  float* q      = (float*)(ws + o_q);
  float* v      = (float*)(ws + o_v);
  float* Wh     = (float*)(ws + o_Wh);
  float* Hcat   = (float*)(ws + o_Hcat);
  float* T4     = (float*)(ws + o_T4);
  float* T6     = (float*)(ws + o_T6);
  float* Z0     = (float*)(ws + o_Z0);
  float* sum1 = stats,       *ssq1 = stats + 128;
  float* sum2 = stats + 256, *ssq2 = stats + 512;
  float* sum3 = stats + 768, *ssq3 = stats + 896;

  hipMemsetAsync(ws, 0, zero_bytes, stream);

  k_detect<<<512, 256, 0, stream>>>((const unsigned short*)X, flag);

  k_proj_qv<<<(64 * N_) / 4, 256, 0, stream>>>(X, Wq, Wv, q, v, flag);
  k_whg<<<dim3(ROWS / 64, 8), 256, 0, stream>>>(X, Ws, Wh, S, flag);

  k_scatter2<<<(16 * NE) / 256, 256, 0, stream>>>(A, fill, colbuf);

  k_attn2<<<16 * N_, 256, 0, stream>>>(q, v, Wh, S, fill, colbuf, Hcat);

  k_mm1g<<<ROWS / 32, 256, 0, stream>>>(Hcat, We1, X, T4, sum1, ssq1, flag);
  k_lin0g<<<dim3(ROWS / 32, 2), 256, 0, stream>>>(T4, Wl0, Z0, sum1, ssq1, sum2, ssq2, flag);
  k_lin1g<<<ROWS / 32, 256, 0, stream>>>(Z0, Wl1, T4, T6, sum2, ssq2, sum1, ssq1,
                                         sum3, ssq3, flag);
  k_norm_out<<<(ROWS * F_) / 256, 256, 0, stream>>>(T6, d_out, sum3, ssq3, flag);

  (void)in_sizes; (void)n_in; (void)out_size; (void)ws_size;
}

// Round 7
// 249.627 us; speedup vs baseline: 1.0695x; 1.0695x over previous
//
#include <hip/hip_runtime.h>
#include <hip/hip_bf16.h>

#define B_    8
#define N_    1024
#define F_    128
#define G_    64
#define EC    2
#define NHD   4
#define NE    16384
#define L0_   256
#define ALPHA_ 0.5f
#define EPS_   1e-5f
#define SLOPE_ 0.01f
#define ROWS  (B_*N_)      // 8192
#define C1    (NHD*EC*G_)  // 512

__device__ __forceinline__ float ldv(const float* p, size_t i) { return p[i]; }
__device__ __forceinline__ float ldv(const __hip_bfloat16* p, size_t i) {
  unsigned short u = *(const unsigned short*)&p[i];
  return __uint_as_float((unsigned)u << 16);
}
__device__ __forceinline__ void ld4(const float* p, float& a, float& b, float& c, float& d) {
  float4 v = *(const float4*)p; a = v.x; b = v.y; c = v.z; d = v.w;
}
__device__ __forceinline__ void ld4(const __hip_bfloat16* p, float& a, float& b, float& c, float& d) {
  ushort4 v = *(const ushort4*)p;
  a = __uint_as_float((unsigned)v.x << 16); b = __uint_as_float((unsigned)v.y << 16);
  c = __uint_as_float((unsigned)v.z << 16); d = __uint_as_float((unsigned)v.w << 16);
}

__device__ __forceinline__ float wmaxf(float v) {
#pragma unroll
  for (int o = 32; o; o >>= 1) v = fmaxf(v, __shfl_xor(v, o, 64));
  return v;
}
__device__ __forceinline__ float wsumf(float v) {
#pragma unroll
  for (int o = 32; o; o >>= 1) v += __shfl_xor(v, o, 64);
  return v;
}

// ---- dtype detector (proven round 2 — do not change logic) ----------------
__global__ void k_detect(const unsigned short* Xu, int* flag) {
  int idx = blockIdx.x * 256 + threadIdx.x;
  unsigned short u = Xu[idx];
  if ((u & 0x7F80u) == 0x7F80u) atomicOr(flag, 1);
}

// ---- q/v projections ------------------------------------------------------
template <typename T>
__device__ __forceinline__ void proj_qv_body(const T* X, const T* Wq, const T* Wv,
                                             float* q, float* v) {
  int tid = threadIdx.x, lane = tid & 63, w = tid >> 6;
  int r = blockIdx.x * 4 + w;
  int n = r & (N_ - 1); int beh = r >> 10; int be = beh >> 2, h = beh & 3;
  int b = be >> 1, e = be & 1;
  const T* xr = X + ((size_t)(b * N_ + n)) * F_;
  const T* wq = Wq + (e * NHD + h) * F_;
  const T* wv = Wv + (e * NHD + h) * F_;
  float x0 = ldv(xr, lane), x1 = ldv(xr, lane + 64);
  float aq = x0 * ldv(wq, lane) + x1 * ldv(wq, lane + 64);
  float av = x0 * ldv(wv, lane) + x1 * ldv(wv, lane + 64);
  aq = wsumf(aq); av = wsumf(av);
  if (lane == 0) { q[r] = aq; v[r] = av; }
}
__global__ void k_proj_qv(const void* X, const void* Wq, const void* Wv,
                          float* q, float* v, const int* flag) {
  if (*flag) proj_qv_body<float>((const float*)X, (const float*)Wq, (const float*)Wv, q, v);
  else       proj_qv_body<__hip_bfloat16>((const __hip_bfloat16*)X, (const __hip_bfloat16*)Wq,
                                          (const __hip_bfloat16*)Wv, q, v);
}

// ---- Wh projection GEMM + fused column-sum S (round-5 simple loop) --------
template <typename TW>
__device__ __forceinline__ void wh_body(const TW* X, const TW* Wsrc, float* Wh, float* S,
                                        float* smem) {
  constexpr int KDIM = 128, KT = 64, NCOL = 64, RT = 64, RTP = 68, NP = 68;
  float* As = smem;                 // KT*RTP
  float* Ws = smem + KT * RTP;      // KT*NP
  int tid = threadIdx.x, tx = tid & 15, ty = tid >> 4;
  int row0 = blockIdx.x * RT; int eh = blockIdx.y;
  const TW* Wp = Wsrc + (size_t)eh * KDIM * NCOL;
  float acc[4][4] = {};
  for (int k0 = 0; k0 < KDIM; k0 += KT) {
    for (int t = tid; t < RT * KT / 4; t += 256) {
      int rr = t >> 4, k4 = t & 15;
      float a0, a1, a2, a3;
      ld4(X + (size_t)(row0 + rr) * KDIM + k0 + k4 * 4, a0, a1, a2, a3);
      As[(k4 * 4 + 0) * RTP + rr] = a0; As[(k4 * 4 + 1) * RTP + rr] = a1;
      As[(k4 * 4 + 2) * RTP + rr] = a2; As[(k4 * 4 + 3) * RTP + rr] = a3;
    }
    for (int t = tid; t < KT * NCOL / 4; t += 256) {
      int col4 = t & 15, k = t >> 4;
      float w0, w1, w2, w3;
      ld4(Wp + (size_t)(k0 + k) * NCOL + col4 * 4, w0, w1, w2, w3);
      *(float4*)(Ws + k * NP + col4 * 4) = make_float4(w0, w1, w2, w3);
    }
    __syncthreads();
#pragma unroll 4
    for (int k = 0; k < KT; ++k) {
      float4 av = *(const float4*)(As + k * RTP + ty * 4);
      float4 wv = *(const float4*)(Ws + k * NP + tx * 4);
      acc[0][0] += av.x * wv.x; acc[0][1] += av.x * wv.y; acc[0][2] += av.x * wv.z; acc[0][3] += av.x * wv.w;
      acc[1][0] += av.y * wv.x; acc[1][1] += av.y * wv.y; acc[1][2] += av.y * wv.z; acc[1][3] += av.y * wv.w;
      acc[2][0] += av.z * wv.x; acc[2][1] += av.z * wv.y; acc[2][2] += av.z * wv.z; acc[2][3] += av.z * wv.w;
      acc[3][0] += av.w * wv.x; acc[3][1] += av.w * wv.y; acc[3][2] += av.w * wv.z; acc[3][3] += av.w * wv.w;
    }
    __syncthreads();
  }
  int b = row0 >> 10;           // 64-row tiles never cross a batch boundary
  float colS[4] = {};
#pragma unroll
  for (int i = 0; i < 4; ++i) {
    int r = row0 + ty * 4 + i; int n = r & (N_ - 1);
    size_t base = ((size_t)(b * 8 + eh) * N_ + n) * G_ + tx * 4;
#pragma unroll
    for (int j = 0; j < 4; ++j) { Wh[base + j] = acc[i][j]; colS[j] += acc[i][j]; }
  }
  float* red = smem;            // 16*64 floats; safe after last sync
#pragma unroll
  for (int j = 0; j < 4; ++j) red[ty * 64 + tx * 4 + j] = colS[j];
  __syncthreads();
  if (tid < 64) {
    float s = 0.f;
#pragma unroll
    for (int t = 0; t < 16; ++t) s += red[t * 64 + tid];
    atomicAdd(&S[(size_t)(b * 8 + eh) * G_ + tid], s);
  }
}
__global__ __launch_bounds__(256) void k_whg(const void* X, const void* Ws, float* Wh,
                                             float* S, const int* flag) {
  __shared__ __align__(16) float smem[64 * 68 + 64 * 68];
  if (*flag) wh_body<float>((const float*)X, (const float*)Ws, Wh, S, smem);
  else       wh_body<__hip_bfloat16>((const __hip_bfloat16*)X, (const __hip_bfloat16*)Ws, Wh, S, smem);
}

// ---- adjacency: direct fixed-capacity buckets -----------------------------
__global__ void k_scatter2(const int* A, int* fill, int* colbuf) {
  int idx = blockIdx.x * 256 + threadIdx.x;    // 16*NE
  int be = idx >> 14, i = idx & (NE - 1);
  int row = A[(size_t)(be * 2) * NE + i];
  int col = A[(size_t)(be * 2 + 1) * NE + i];
  int p = atomicAdd(&fill[be * N_ + row], 1);
  if (p < 64) colbuf[((size_t)(be * N_ + row)) * 64 + p] = col;
}

// ---- sparse attention: g-vectorized gather --------------------------------
// lane = (edge-subgroup eg = lane>>4, g-quad g4 = (lane&15)*4); 4 edges/iter,
// float4 Wh loads; 2 shfl_xor steps fold the 4 edge-subgroups.
__global__ __launch_bounds__(256) void k_attn2(const float* q, const float* v, const float* Wh,
                                               const float* S, const int* fill,
                                               const int* colbuf, float* Hcat) {
  __shared__ int s_col[64];
  __shared__ int s_cnt[64];
  __shared__ int s_ld;
  __shared__ float s_w[4][64];
  int tid = threadIdx.x, lane = tid & 63, h = tid >> 6;
  int be = blockIdx.x >> 10, n = blockIdx.x & (N_ - 1);
  int b = be >> 1, e = be & 1;
  if (h == 0) {
    s_col[lane] = 0;                       // pad for vectorized gather (wk=0 there)
    int L = fill[be * N_ + n];
    int Lc = (L > 64) ? 64 : L;
    int myc = (lane < Lc) ? colbuf[((size_t)(be * N_ + n)) * 64 + lane] : -1;
    int cct = 0, firstk = 64;
    for (int k = 0; k < Lc; ++k) {
      int ck = __shfl(myc, k, 64);
      if (myc >= 0 && ck == myc) { cct++; if (k < firstk) firstk = k; }
    }
    bool act = (lane < Lc) && (firstk == lane);
    unsigned long long mask = __ballot(act);
    int pos = __popcll(mask & ((1ull << lane) - 1ull));
    if (act) { s_col[pos] = myc; s_cnt[pos] = cct; }
    if (lane == 0) s_ld = __popcll(mask);
  }
  __syncthreads();
  int Ld = s_ld;
  int beh = (be << 2) | h;
  float qn = q[beh * N_ + n];
  float sc = -1e30f;
  if (lane < Ld) {
    float t = qn * v[beh * N_ + s_col[lane]] * (float)s_cnt[lane];
    sc = (t >= 0.f) ? t : SLOPE_ * t;
  }
  float M = fmaxf(0.f, wmaxf(sc));
  float Ej = (lane < Ld) ? expf(sc - M) : 0.f;
  float sumE = wsumf(Ej);
  float em = expf(-M);
  float Z = (float)(N_ - Ld) * em + sumE;
  s_w[h][lane] = (lane < Ld) ? (Ej - em) / Z : 0.f;   // same-wave write->read: in order
  int eg = lane >> 4, g4 = (lane & 15) << 2;
  float4 accv = make_float4(0.f, 0.f, 0.f, 0.f);
  if (eg == 0) {
    float4 s4 = *(const float4*)&S[(size_t)beh * G_ + g4];
    float sca = em / Z;
    accv.x = sca * s4.x; accv.y = sca * s4.y; accv.z = sca * s4.z; accv.w = sca * s4.w;
  }
  const float* WhB = Wh + (size_t)beh * N_ * G_;
  for (int k0 = 0; k0 < Ld; k0 += 4) {
    int kk = k0 + eg;
    float wk = s_w[h][kk];                 // 0 beyond Ld (padded)
    int ck = s_col[kk];                    // 0 beyond Ld (safe address)
    float4 x = *(const float4*)&WhB[(size_t)ck * G_ + g4];
    accv.x += wk * x.x; accv.y += wk * x.y; accv.z += wk * x.z; accv.w += wk * x.w;
  }
  accv.x += __shfl_xor(accv.x, 16, 64); accv.y += __shfl_xor(accv.y, 16, 64);
  accv.z += __shfl_xor(accv.z, 16, 64); accv.w += __shfl_xor(accv.w, 16, 64);
  accv.x += __shfl_xor(accv.x, 32, 64); accv.y += __shfl_xor(accv.y, 32, 64);
  accv.z += __shfl_xor(accv.z, 32, 64); accv.w += __shfl_xor(accv.w, 32, 64);
  if (lane < 16)
    *(float4*)&Hcat[((size_t)(b * N_ + n)) * C1 + h * (EC * G_) + e * G_ + g4] = accv;
}

// ---- generic 32xNCOL tiled GEMM with fused BN-stats epilogue --------------
// NCOL=64 tiles -> grid 2-4 blocks/CU (round-5 grid of 256 was 1/CU: the
// occupancy bottleneck). 2 rows x 4 cols per thread; simple inner loop
// (manual ILP rotation regressed in round 6 — issue-bound, not latency-bound).
template <int KDIM, int KT, int NCOL, int MODEA, int EP, typename TW>
__device__ __forceinline__ void gemm_body(
    const float* __restrict__ Araw, const TW* __restrict__ W, const TW* __restrict__ Xsrc,
    const float* __restrict__ Res,
    const float* sAsum, const float* sAssq, const float* sRsum, const float* sRssq,
    float* oSum, float* oSsq,
    float* __restrict__ C, int cstride, float* smem) {
  constexpr int RT = 32, RTP = 36, NP = NCOL + 4;
  float* As = smem;               // KT*RTP
  float* Ws = smem + KT * RTP;    // KT*NP
  int tid = threadIdx.x, tx = tid & 15, ty = tid >> 4;   // 16 col-quads, 16 row-pairs
  int row0 = blockIdx.x * RT;
  int col0 = blockIdx.y * NCOL;
  float acc[2][4] = {};
  for (int k0 = 0; k0 < KDIM; k0 += KT) {
    for (int t = tid; t < RT * KT / 4; t += 256) {
      int rr = t / (KT / 4), k4 = t % (KT / 4);
      float4 val = *(const float4*)(Araw + (size_t)(row0 + rr) * KDIM + k0 + k4 * 4);
      if (MODEA) {
        float* vp = &val.x;
#pragma unroll
        for (int j = 0; j < 4; ++j) {
          int c = k0 + k4 * 4 + j;
          float mean = sAsum[c] * (1.f / ROWS);
          float var = sAssq[c] * (1.f / ROWS) - mean * mean;
          float y = (vp[j] - mean) * rsqrtf(var + EPS_);
          if (MODEA == 2) y = (y > 0.f) ? y : (expf(y) - 1.f);
          vp[j] = y;
        }
      }
      As[(k4 * 4 + 0) * RTP + rr] = val.x; As[(k4 * 4 + 1) * RTP + rr] = val.y;
      As[(k4 * 4 + 2) * RTP + rr] = val.z; As[(k4 * 4 + 3) * RTP + rr] = val.w;
    }
    for (int t = tid; t < NCOL * KT / 4; t += 256) {
      int col = t % NCOL, k4 = t / NCOL;
      float w0, w1, w2, w3;
      ld4(W + (size_t)(col0 + col) * KDIM + k0 + k4 * 4, w0, w1, w2, w3);
      Ws[(k4 * 4 + 0) * NP + col] = w0; Ws[(k4 * 4 + 1) * NP + col] = w1;
      Ws[(k4 * 4 + 2) * NP + col] = w2; Ws[(k4 * 4 + 3) * NP + col] = w3;
    }
    __syncthreads();
#pragma unroll 8
    for (int k = 0; k < KT; ++k) {
      float2 a2 = *(const float2*)(As + k * RTP + ty * 2);
      float4 wv = *(const float4*)(Ws + k * NP + tx * 4);
      acc[0][0] += a2.x * wv.x; acc[0][1] += a2.x * wv.y; acc[0][2] += a2.x * wv.z; acc[0][3] += a2.x * wv.w;
      acc[1][0] += a2.y * wv.x; acc[1][1] += a2.y * wv.y; acc[1][2] += a2.y * wv.z; acc[1][3] += a2.y * wv.w;
    }
    __syncthreads();
  }
  float colS[4] = {}, colS2[4] = {};
#pragma unroll
  for (int i = 0; i < 2; ++i) {
    int r = row0 + ty * 2 + i;
#pragma unroll
    for (int j = 0; j < 4; ++j) {
      int c = col0 + tx * 4 + j;
      float o = acc[i][j];
      if (EP == 1) {
        o = fmaxf(o, 0.f);
        o = (1.f - ALPHA_) * o + ALPHA_ * ldv(Xsrc, (size_t)r * F_ + c);
      } else if (EP == 2) {
        float x = Res[(size_t)r * 128 + c];
        float mean = sRsum[c] * (1.f / ROWS);
        float var = sRssq[c] * (1.f / ROWS) - mean * mean;
        o += (x - mean) * rsqrtf(var + EPS_);
      }
      C[(size_t)r * cstride + c] = o;
      colS[j] += o; colS2[j] += o * o;
    }
  }
  float* red = smem;              // 16 * NCOL * 2 floats; safe after last sync
#pragma unroll
  for (int j = 0; j < 4; ++j) {
    red[ty * (NCOL * 2) + (tx * 4 + j) * 2 + 0] = colS[j];
    red[ty * (NCOL * 2) + (tx * 4 + j) * 2 + 1] = colS2[j];
  }
  __syncthreads();
  if (tid < NCOL) {
    float s = 0.f, s2 = 0.f;
#pragma unroll
    for (int t = 0; t < 16; ++t) {
      s += red[t * (NCOL * 2) + tid * 2]; s2 += red[t * (NCOL * 2) + tid * 2 + 1];
    }
    atomicAdd(&oSum[col0 + tid], s); atomicAdd(&oSsq[col0 + tid], s2);
  }
}

#define GEMM_SMEM (64 * 36 + 64 * 68)

__global__ __launch_bounds__(256) void k_mm1g(const float* A, const void* W, const void* X,
                                              float* C, float* oSum, float* oSsq,
                                              const int* flag) {
  __shared__ __align__(16) float smem[GEMM_SMEM];
  if (*flag)
    gemm_body<512, 64, 64, 0, 1, float>(A, (const float*)W, (const float*)X, nullptr,
                                        nullptr, nullptr, nullptr, nullptr, oSum, oSsq,
                                        C, 128, smem);
  else
    gemm_body<512, 64, 64, 0, 1, __hip_bfloat16>(A, (const __hip_bfloat16*)W,
                                                 (const __hip_bfloat16*)X, nullptr,
                                                 nullptr, nullptr, nullptr, nullptr, oSum, oSsq,
                                                 C, 128, smem);
}
__global__ __launch_bounds__(256) void k_lin0g(const float* A, const void* W, float* C,
                                               const float* s1sum, const float* s1ssq,
                                               float* oSum, float* oSsq, const int* flag) {
  __shared__ __align__(16) float smem[GEMM_SMEM];
  if (*flag)
    gemm_body<128, 64, 64, 1, 0, float>(A, (const float*)W, nullptr, nullptr,
                                        s1sum, s1ssq, nullptr, nullptr, oSum, oSsq,
                                        C, 256, smem);
  else
    gemm_body<128, 64, 64, 1, 0, __hip_bfloat16>(A, (const __hip_bfloat16*)W, nullptr, nullptr,
                                                 s1sum, s1ssq, nullptr, nullptr, oSum, oSsq,
                                                 C, 256, smem);
}
__global__ __launch_bounds__(256) void k_lin1g(const float* A, const void* W, const float* Res,
                                               float* C, const float* s2sum, const float* s2ssq,
                                               const float* s1sum, const float* s1ssq,
                                               float* oSum, float* oSsq, const int* flag) {
  __shared__ __align__(16) float smem[GEMM_SMEM];
  if (*flag)
    gemm_body<256, 64, 64, 2, 2, float>(A, (const float*)W, nullptr, Res,
                                        s2sum, s2ssq, s1sum, s1ssq, oSum, oSsq,
                                        C, 128, smem);
  else
    gemm_body<256, 64, 64, 2, 2, __hip_bfloat16>(A, (const __hip_bfloat16*)W, nullptr, Res,
                                                 s2sum, s2ssq, s1sum, s1ssq, oSum, oSsq,
                                                 C, 128, smem);
}

__global__ void k_norm_out(const float* in, void* out, const float* sum, const float* ssq,
                           const int* flag) {
  int idx = blockIdx.x * 256 + threadIdx.x; int c = idx & (F_ - 1);
  float mean = sum[c] * (1.f / ROWS);
  float var = ssq[c] * (1.f / ROWS) - mean * mean;
  float y = (in[idx] - mean) * rsqrtf(var + EPS_);
  if (*flag) ((float*)out)[idx] = y;
  else       ((__hip_bfloat16*)out)[idx] = __float2bfloat16(y);
}

// ---------------------------------------------------------------------------
extern "C" void kernel_launch(void* const* d_in, const int* in_sizes, int n_in,
                              void* d_out, int out_size, void* d_ws, size_t ws_size,
                              hipStream_t stream) {
  const int* A    = (const int*)d_in[0];
  const void* X   = d_in[1];
  const void* Ws  = d_in[2];
  const void* Wq  = d_in[3];
  const void* Wv  = d_in[4];
  const void* We1 = d_in[5];
  const void* Wl0 = d_in[6];
  const void* Wl1 = d_in[7];

  char* ws = (char*)d_ws;
  size_t off = 0;
  auto alloc = [&](size_t bytes) { size_t o = off; off += (bytes + 255) & ~(size_t)255; return o; };
  size_t o_fill   = alloc(16 * N_ * 4);            // zeroed
  size_t o_stats  = alloc(1024 * 4);               // zeroed
  size_t o_flag   = alloc(256);                    // zeroed
  size_t o_S      = alloc((size_t)64 * G_ * 4);    // zeroed (atomic accum)
  size_t zero_bytes = off;
  size_t o_colbuf = alloc((size_t)16 * N_ * 64 * 4);    // 4 MiB
  size_t o_q      = alloc((size_t)64 * N_ * 4);
  size_t o_v      = alloc((size_t)64 * N_ * 4);
  size_t o_Wh     = alloc((size_t)64 * N_ * G_ * 4);    // 16 MiB
  size_t o_Hcat   = alloc((size_t)ROWS * C1 * 4);       // 16 MiB
  size_t o_T4     = alloc((size_t)ROWS * F_ * 4);
  size_t o_T6     = alloc((size_t)ROWS * F_ * 4);
  size_t o_Z0     = alloc((size_t)ROWS * L0_ * 4);

  int*   fill   = (int*)(ws + o_fill);
  float* stats  = (float*)(ws + o_stats);
  int*   flag   = (int*)(ws + o_flag);
  float* S      = (float*)(ws + o_S);
  int*   colbuf = (int*)(ws + o_colbuf);
  float* q      = (float*)(ws + o_q);
  float* v      = (float*)(ws + o_v);
  float* Wh     = (float*)(ws + o_Wh);
  float* Hcat   = (float*)(ws + o_Hcat);
  float* T4     = (float*)(ws + o_T4);
  float* T6     = (float*)(ws + o_T6);
  float* Z0     = (float*)(ws + o_Z0);
  float* sum1 = stats,       *ssq1 = stats + 128;
  float* sum2 = stats + 256, *ssq2 = stats + 512;
  float* sum3 = stats + 768, *ssq3 = stats + 896;

  hipMemsetAsync(ws, 0, zero_bytes, stream);

  k_detect<<<512, 256, 0, stream>>>((const unsigned short*)X, flag);

  k_proj_qv<<<(64 * N_) / 4, 256, 0, stream>>>(X, Wq, Wv, q, v, flag);
  k_whg<<<dim3(ROWS / 64, 8), 256, 0, stream>>>(X, Ws, Wh, S, flag);

  k_scatter2<<<(16 * NE) / 256, 256, 0, stream>>>(A, fill, colbuf);

  k_attn2<<<16 * N_, 256, 0, stream>>>(q, v, Wh, S, fill, colbuf, Hcat);

  k_mm1g<<<dim3(ROWS / 32, 2), 256, 0, stream>>>(Hcat, We1, X, T4, sum1, ssq1, flag);
  k_lin0g<<<dim3(ROWS / 32, 4), 256, 0, stream>>>(T4, Wl0, Z0, sum1, ssq1, sum2, ssq2, flag);
  k_lin1g<<<dim3(ROWS / 32, 2), 256, 0, stream>>>(Z0, Wl1, T4, T6, sum2, ssq2, sum1, ssq1,
                                                  sum3, ssq3, flag);
  k_norm_out<<<(ROWS * F_) / 256, 256, 0, stream>>>(T6, d_out, sum3, ssq3, flag);

  (void)in_sizes; (void)n_in; (void)out_size; (void)ws_size;
}

// Round 8
// 247.275 us; speedup vs baseline: 1.0797x; 1.0095x over previous
//
#include <hip/hip_runtime.h>
#include <hip/hip_bf16.h>

#define B_    8
#define N_    1024
#define F_    128
#define G_    64
#define EC    2
#define NHD   4
#define NE    16384
#define L0_   256
#define ALPHA_ 0.5f
#define EPS_   1e-5f
#define SLOPE_ 0.01f
#define ROWS  (B_*N_)      // 8192
#define C1    (NHD*EC*G_)  // 512

typedef __attribute__((ext_vector_type(8))) short s8bf;   // 8 bf16 (4 VGPRs)
typedef __attribute__((ext_vector_type(4))) float f32x4;  // MFMA accumulator

__device__ __forceinline__ float ldv(const float* p, size_t i) { return p[i]; }
__device__ __forceinline__ float ldv(const __hip_bfloat16* p, size_t i) {
  unsigned short u = *(const unsigned short*)&p[i];
  return __uint_as_float((unsigned)u << 16);
}
__device__ __forceinline__ unsigned short f2b(float f) {   // RNE f32 -> bf16
  unsigned u = __float_as_uint(f);
  u = (u + 0x7FFFu + ((u >> 16) & 1u)) >> 16;
  return (unsigned short)u;
}
__device__ __forceinline__ float b2f(unsigned short u) {
  return __uint_as_float((unsigned)u << 16);
}

__device__ __forceinline__ float wmaxf(float v) {
#pragma unroll
  for (int o = 32; o; o >>= 1) v = fmaxf(v, __shfl_xor(v, o, 64));
  return v;
}
__device__ __forceinline__ float wsumf(float v) {
#pragma unroll
  for (int o = 32; o; o >>= 1) v += __shfl_xor(v, o, 64);
  return v;
}

// ---- dtype detector (proven round 2 — do not change logic) ----------------
__global__ void k_detect(const unsigned short* Xu, int* flag) {
  int idx = blockIdx.x * 256 + threadIdx.x;
  unsigned short u = Xu[idx];
  if ((u & 0x7F80u) == 0x7F80u) atomicOr(flag, 1);
}

// ---- bf16 conversion of X / Ws(transposed) / We1 / Wl1 --------------------
__device__ __forceinline__ unsigned short cvt_at(const void* p, size_t i, int isf) {
  return isf ? f2b(((const float*)p)[i]) : ((const unsigned short*)p)[i];
}
__global__ void k_cvtw(const void* X, const void* Ws, const void* We1, const void* Wl1,
                       unsigned short* Xb, unsigned short* Wsb, unsigned short* We1b,
                       unsigned short* Wl1b, const int* flag) {
  int isf = *flag;
  int bid = blockIdx.x, t = threadIdx.x;
  if (bid < 4096) {                       // X: 8192*128
    int i = bid * 256 + t; Xb[i] = cvt_at(X, i, isf);
  } else if (bid < 4352) {                // We1: 128*512
    int i = (bid - 4096) * 256 + t; We1b[i] = cvt_at(We1, i, isf);
  } else if (bid < 4480) {                // Wl1: 128*256
    int i = (bid - 4352) * 256 + t; Wl1b[i] = cvt_at(Wl1, i, isf);
  } else {                                // Ws: [eh][f][g] -> Wsb [eh][g][f]
    int i = (bid - 4480) * 256 + t;       // 0..65535
    int eh = i >> 13, rem = i & 8191;
    int g = rem >> 7, f = rem & 127;
    Wsb[eh * 8192 + g * 128 + f] = cvt_at(Ws, (size_t)eh * 8192 + f * 64 + g, isf);
  }
}

// ---- q/v projections (f32-accurate, unchanged) ----------------------------
template <typename T>
__device__ __forceinline__ void proj_qv_body(const T* X, const T* Wq, const T* Wv,
                                             float* q, float* v) {
  int tid = threadIdx.x, lane = tid & 63, w = tid >> 6;
  int r = blockIdx.x * 4 + w;
  int n = r & (N_ - 1); int beh = r >> 10; int be = beh >> 2, h = beh & 3;
  int b = be >> 1, e = be & 1;
  const T* xr = X + ((size_t)(b * N_ + n)) * F_;
  const T* wq = Wq + (e * NHD + h) * F_;
  const T* wv = Wv + (e * NHD + h) * F_;
  float x0 = ldv(xr, lane), x1 = ldv(xr, lane + 64);
  float aq = x0 * ldv(wq, lane) + x1 * ldv(wq, lane + 64);
  float av = x0 * ldv(wv, lane) + x1 * ldv(wv, lane + 64);
  aq = wsumf(aq); av = wsumf(av);
  if (lane == 0) { q[r] = aq; v[r] = av; }
}
__global__ void k_proj_qv(const void* X, const void* Wq, const void* Wv,
                          float* q, float* v, const int* flag) {
  if (*flag) proj_qv_body<float>((const float*)X, (const float*)Wq, (const float*)Wv, q, v);
  else       proj_qv_body<__hip_bfloat16>((const __hip_bfloat16*)X, (const __hip_bfloat16*)Wq,
                                          (const __hip_bfloat16*)Wv, q, v);
}

// ---- MFMA core: one wave computes a 16x64 tile, no LDS, no barriers -------
// A [M][K] bf16 row-major; W [Ncols][K] bf16 row-major (= B^T).
// Verified layouts (learn_hip m89/m120): A-frag A[m=lane&15][k=quad*8+j];
// B-frag = W row (lane&15 -> col) 8 contiguous k; C/D col=lane&15,row=quad*4+i.
template <int K>
__device__ __forceinline__ void mfma_core(const unsigned short* __restrict__ Ab,
                                          const unsigned short* __restrict__ Wb,
                                          int r0, int c0, f32x4* acc) {
  int lane = threadIdx.x & 63; int q = lane >> 4, c15 = lane & 15;
  constexpr int RS = K / 8;                        // row stride in s8bf units
  const s8bf* ap = (const s8bf*)Ab + (size_t)(r0 + c15) * RS + q;
  const s8bf* bp = (const s8bf*)Wb + (size_t)(c0 + c15) * RS + q;
#pragma unroll
  for (int ks = 0; ks < K / 32; ++ks) {
    s8bf a  = ap[ks * 4];
    s8bf b0 = bp[ks * 4];
    s8bf b1 = bp[16 * RS + ks * 4];
    s8bf b2 = bp[32 * RS + ks * 4];
    s8bf b3 = bp[48 * RS + ks * 4];
    acc[0] = __builtin_amdgcn_mfma_f32_16x16x32_bf16(a, b0, acc[0], 0, 0, 0);
    acc[1] = __builtin_amdgcn_mfma_f32_16x16x32_bf16(a, b1, acc[1], 0, 0, 0);
    acc[2] = __builtin_amdgcn_mfma_f32_16x16x32_bf16(a, b2, acc[2], 0, 0, 0);
    acc[3] = __builtin_amdgcn_mfma_f32_16x16x32_bf16(a, b3, acc[3], 0, 0, 0);
  }
}

// ---- Wh projection (MFMA) + fused column-sum S ----------------------------
__global__ __launch_bounds__(64) void k_whm(const unsigned short* Xb,
                                            const unsigned short* Wsb,
                                            float* Wh, float* S) {
  int r0 = blockIdx.x * 16; int eh = blockIdx.y;
  f32x4 acc[4] = {{0,0,0,0},{0,0,0,0},{0,0,0,0},{0,0,0,0}};
  mfma_core<128>(Xb, Wsb + eh * 8192, r0, 0, acc);
  int lane = threadIdx.x, q = lane >> 4, c15 = lane & 15;
  int b = r0 >> 10; int beh = b * 8 + eh;
  float* WhB = Wh + ((size_t)beh * N_ + (r0 & (N_ - 1))) * G_;
#pragma unroll
  for (int nc = 0; nc < 4; ++nc) {
    float s = 0.f;
#pragma unroll
    for (int i = 0; i < 4; ++i) {
      float o = acc[nc][i];
      WhB[(size_t)(q * 4 + i) * G_ + nc * 16 + c15] = o;
      s += o;
    }
    s += __shfl_xor(s, 16, 64); s += __shfl_xor(s, 32, 64);
    if (lane < 16) atomicAdd(&S[(size_t)beh * G_ + nc * 16 + lane], s);
  }
}

// ---- adjacency: direct fixed-capacity buckets -----------------------------
__global__ void k_scatter2(const int* A, int* fill, int* colbuf) {
  int idx = blockIdx.x * 256 + threadIdx.x;    // 16*NE
  int be = idx >> 14, i = idx & (NE - 1);
  int row = A[(size_t)(be * 2) * NE + i];
  int col = A[(size_t)(be * 2 + 1) * NE + i];
  int p = atomicAdd(&fill[be * N_ + row], 1);
  if (p < 64) colbuf[((size_t)(be * N_ + row)) * 64 + p] = col;
}

// ---- sparse attention (round-7 g-vectorized; output now bf16) -------------
__global__ __launch_bounds__(256) void k_attn2(const float* q, const float* v, const float* Wh,
                                               const float* S, const int* fill,
                                               const int* colbuf, unsigned short* Hcatb) {
  __shared__ int s_col[64];
  __shared__ int s_cnt[64];
  __shared__ int s_ld;
  __shared__ float s_w[4][64];
  int tid = threadIdx.x, lane = tid & 63, h = tid >> 6;
  int be = blockIdx.x >> 10, n = blockIdx.x & (N_ - 1);
  int b = be >> 1, e = be & 1;
  if (h == 0) {
    s_col[lane] = 0;
    int L = fill[be * N_ + n];
    int Lc = (L > 64) ? 64 : L;
    int myc = (lane < Lc) ? colbuf[((size_t)(be * N_ + n)) * 64 + lane] : -1;
    int cct = 0, firstk = 64;
    for (int k = 0; k < Lc; ++k) {
      int ck = __shfl(myc, k, 64);
      if (myc >= 0 && ck == myc) { cct++; if (k < firstk) firstk = k; }
    }
    bool act = (lane < Lc) && (firstk == lane);
    unsigned long long mask = __ballot(act);
    int pos = __popcll(mask & ((1ull << lane) - 1ull));
    if (act) { s_col[pos] = myc; s_cnt[pos] = cct; }
    if (lane == 0) s_ld = __popcll(mask);
  }
  __syncthreads();
  int Ld = s_ld;
  int beh = (be << 2) | h;
  float qn = q[beh * N_ + n];
  float sc = -1e30f;
  if (lane < Ld) {
    float t = qn * v[beh * N_ + s_col[lane]] * (float)s_cnt[lane];
    sc = (t >= 0.f) ? t : SLOPE_ * t;
  }
  float M = fmaxf(0.f, wmaxf(sc));
  float Ej = (lane < Ld) ? expf(sc - M) : 0.f;
  float sumE = wsumf(Ej);
  float em = expf(-M);
  float Z = (float)(N_ - Ld) * em + sumE;
  s_w[h][lane] = (lane < Ld) ? (Ej - em) / Z : 0.f;
  int eg = lane >> 4, g4 = (lane & 15) << 2;
  float4 accv = make_float4(0.f, 0.f, 0.f, 0.f);
  if (eg == 0) {
    float4 s4 = *(const float4*)&S[(size_t)beh * G_ + g4];
    float sca = em / Z;
    accv.x = sca * s4.x; accv.y = sca * s4.y; accv.z = sca * s4.z; accv.w = sca * s4.w;
  }
  const float* WhB = Wh + (size_t)beh * N_ * G_;
  for (int k0 = 0; k0 < Ld; k0 += 4) {
    int kk = k0 + eg;
    float wk = s_w[h][kk];
    int ck = s_col[kk];
    float4 x = *(const float4*)&WhB[(size_t)ck * G_ + g4];
    accv.x += wk * x.x; accv.y += wk * x.y; accv.z += wk * x.z; accv.w += wk * x.w;
  }
  accv.x += __shfl_xor(accv.x, 16, 64); accv.y += __shfl_xor(accv.y, 16, 64);
  accv.z += __shfl_xor(accv.z, 16, 64); accv.w += __shfl_xor(accv.w, 16, 64);
  accv.x += __shfl_xor(accv.x, 32, 64); accv.y += __shfl_xor(accv.y, 32, 64);
  accv.z += __shfl_xor(accv.z, 32, 64); accv.w += __shfl_xor(accv.w, 32, 64);
  if (lane < 16) {
    ushort4 o;
    o.x = f2b(accv.x); o.y = f2b(accv.y); o.z = f2b(accv.z); o.w = f2b(accv.w);
    *(ushort4*)&Hcatb[((size_t)(b * N_ + n)) * C1 + h * (EC * G_) + e * G_ + g4] = o;
  }
}

// ---- mm1 (MFMA): T4 = 0.5*relu(Hcat @ We^T) + 0.5*X; writes f32+bf16+stats
template <typename TX>
__device__ __forceinline__ void mm1_ep(f32x4* acc, const TX* X, float* T4,
                                       unsigned short* T4b, float* sum1, float* ssq1,
                                       int r0, int c0) {
  int lane = threadIdx.x, q = lane >> 4, c15 = lane & 15;
#pragma unroll
  for (int nc = 0; nc < 4; ++nc) {
    int cc = c0 + nc * 16 + c15;
    float s = 0.f, s2 = 0.f;
#pragma unroll
    for (int i = 0; i < 4; ++i) {
      int rr = r0 + q * 4 + i;
      float o = fmaxf(acc[nc][i], 0.f);
      o = 0.5f * o + 0.5f * ldv(X, (size_t)rr * F_ + cc);
      T4[(size_t)rr * F_ + cc] = o;
      T4b[(size_t)rr * F_ + cc] = f2b(o);
      s += o; s2 += o * o;
    }
    s += __shfl_xor(s, 16, 64); s += __shfl_xor(s, 32, 64);
    s2 += __shfl_xor(s2, 16, 64); s2 += __shfl_xor(s2, 32, 64);
    if (lane < 16) {
      atomicAdd(&sum1[c0 + nc * 16 + lane], s);
      atomicAdd(&ssq1[c0 + nc * 16 + lane], s2);
    }
  }
}
__global__ __launch_bounds__(64) void k_mm1m(const unsigned short* Hcatb,
                                             const unsigned short* We1b, const void* X,
                                             float* T4, unsigned short* T4b,
                                             float* sum1, float* ssq1, const int* flag) {
  int r0 = blockIdx.x * 16, c0 = blockIdx.y * 64;
  f32x4 acc[4] = {{0,0,0,0},{0,0,0,0},{0,0,0,0},{0,0,0,0}};
  mfma_core<512>(Hcatb, We1b, r0, c0, acc);
  if (*flag) mm1_ep<float>(acc, (const float*)X, T4, T4b, sum1, ssq1, r0, c0);
  else       mm1_ep<__hip_bfloat16>(acc, (const __hip_bfloat16*)X, T4, T4b, sum1, ssq1, r0, c0);
}

// ---- fold BN1 into Wl0: W0p = bf16(rs_k*W[c][k]); bias0[c] = sum mean_k*rsW
__global__ void k_fold0(const void* Wl0, const float* sum1, const float* ssq1,
                        unsigned short* W0p, float* bias0, const int* flag) {
  __shared__ float red[2];
  int c = blockIdx.x, k = threadIdx.x;            // 256 blocks x 128 threads
  float mean = sum1[k] * (1.f / ROWS);
  float var = ssq1[k] * (1.f / ROWS) - mean * mean;
  float rs = rsqrtf(var + EPS_);
  float w = (*flag) ? ((const float*)Wl0)[(size_t)c * F_ + k]
                    : b2f(((const unsigned short*)Wl0)[(size_t)c * F_ + k]);
  unsigned short wb = f2b(w * rs);
  W0p[(size_t)c * F_ + k] = wb;
  float part = mean * b2f(wb);
  part = wsumf(part);
  if ((threadIdx.x & 63) == 0) red[threadIdx.x >> 6] = part;
  __syncthreads();
  if (threadIdx.x == 0) bias0[c] = red[0] + red[1];
}

// ---- lin0 (MFMA): Z0 = bn1(T4) @ Wl0^T = T4b@W0p - bias0; stats2 ----------
__global__ __launch_bounds__(64) void k_lin0m(const unsigned short* T4b,
                                              const unsigned short* W0p, const float* bias0,
                                              float* Z0, float* sum2, float* ssq2) {
  int r0 = blockIdx.x * 16, c0 = blockIdx.y * 64;
  f32x4 acc[4] = {{0,0,0,0},{0,0,0,0},{0,0,0,0},{0,0,0,0}};
  mfma_core<128>(T4b, W0p, r0, c0, acc);
  int lane = threadIdx.x, q = lane >> 4, c15 = lane & 15;
#pragma unroll
  for (int nc = 0; nc < 4; ++nc) {
    int cc = c0 + nc * 16 + c15;
    float bia = bias0[cc];
    float s = 0.f, s2 = 0.f;
#pragma unroll
    for (int i = 0; i < 4; ++i) {
      int rr = r0 + q * 4 + i;
      float o = acc[nc][i] - bia;
      Z0[(size_t)rr * L0_ + cc] = o;
      s += o; s2 += o * o;
    }
    s += __shfl_xor(s, 16, 64); s += __shfl_xor(s, 32, 64);
    s2 += __shfl_xor(s2, 16, 64); s2 += __shfl_xor(s2, 32, 64);
    if (lane < 16) {
      atomicAdd(&sum2[c0 + nc * 16 + lane], s);
      atomicAdd(&ssq2[c0 + nc * 16 + lane], s2);
    }
  }
}

// ---- E = bf16(elu(bn2(Z0))) -----------------------------------------------
__global__ void k_elu(const float* Z0, unsigned short* E, const float* sum2,
                      const float* ssq2) {
  int idx = blockIdx.x * 256 + threadIdx.x;
  int c = idx & (L0_ - 1);
  float mean = sum2[c] * (1.f / ROWS);
  float var = ssq2[c] * (1.f / ROWS) - mean * mean;
  float y = (Z0[idx] - mean) * rsqrtf(var + EPS_);
  y = (y > 0.f) ? y : (expf(y) - 1.f);
  E[idx] = f2b(y);
}

// ---- lin1 (MFMA): T6 = bn1(T4) + E @ Wl1^T; stats3 ------------------------
__global__ __launch_bounds__(64) void k_lin1m(const unsigned short* E,
                                              const unsigned short* Wl1b, const float* T4,
                                              const float* sum1, const float* ssq1,
                                              float* T6, float* sum3, float* ssq3) {
  int r0 = blockIdx.x * 16, c0 = blockIdx.y * 64;
  f32x4 acc[4] = {{0,0,0,0},{0,0,0,0},{0,0,0,0},{0,0,0,0}};
  mfma_core<256>(E, Wl1b, r0, c0, acc);
  int lane = threadIdx.x, q = lane >> 4, c15 = lane & 15;
#pragma unroll
  for (int nc = 0; nc < 4; ++nc) {
    int cc = c0 + nc * 16 + c15;
    float mean = sum1[cc] * (1.f / ROWS);
    float var = ssq1[cc] * (1.f / ROWS) - mean * mean;
    float rs = rsqrtf(var + EPS_);
    float s = 0.f, s2 = 0.f;
#pragma unroll
    for (int i = 0; i < 4; ++i) {
      int rr = r0 + q * 4 + i;
      float o = acc[nc][i] + (T4[(size_t)rr * F_ + cc] - mean) * rs;
      T6[(size_t)rr * F_ + cc] = o;
      s += o; s2 += o * o;
    }
    s += __shfl_xor(s, 16, 64); s += __shfl_xor(s, 32, 64);
    s2 += __shfl_xor(s2, 16, 64); s2 += __shfl_xor(s2, 32, 64);
    if (lane < 16) {
      atomicAdd(&sum3[c0 + nc * 16 + lane], s);
      atomicAdd(&ssq3[c0 + nc * 16 + lane], s2);
    }
  }
}

__global__ void k_norm_out(const float* in, void* out, const float* sum, const float* ssq,
                           const int* flag) {
  int idx = blockIdx.x * 256 + threadIdx.x; int c = idx & (F_ - 1);
  float mean = sum[c] * (1.f / ROWS);
  float var = ssq[c] * (1.f / ROWS) - mean * mean;
  float y = (in[idx] - mean) * rsqrtf(var + EPS_);
  if (*flag) ((float*)out)[idx] = y;
  else       ((__hip_bfloat16*)out)[idx] = __float2bfloat16(y);
}

// ---------------------------------------------------------------------------
extern "C" void kernel_launch(void* const* d_in, const int* in_sizes, int n_in,
                              void* d_out, int out_size, void* d_ws, size_t ws_size,
                              hipStream_t stream) {
  const int* A    = (const int*)d_in[0];
  const void* X   = d_in[1];
  const void* Ws  = d_in[2];
  const void* Wq  = d_in[3];
  const void* Wv  = d_in[4];
  const void* We1 = d_in[5];
  const void* Wl0 = d_in[6];
  const void* Wl1 = d_in[7];

  char* ws = (char*)d_ws;
  size_t off = 0;
  auto alloc = [&](size_t bytes) { size_t o = off; off += (bytes + 255) & ~(size_t)255; return o; };
  size_t o_fill   = alloc(16 * N_ * 4);            // zeroed
  size_t o_stats  = alloc(1024 * 4);               // zeroed
  size_t o_flag   = alloc(256);                    // zeroed
  size_t o_S      = alloc((size_t)64 * G_ * 4);    // zeroed (atomic accum)
  size_t zero_bytes = off;
  size_t o_colbuf = alloc((size_t)16 * N_ * 64 * 4);     // 4 MiB
  size_t o_q      = alloc((size_t)64 * N_ * 4);
  size_t o_v      = alloc((size_t)64 * N_ * 4);
  size_t o_Wh     = alloc((size_t)64 * N_ * G_ * 4);     // 16 MiB f32
  size_t o_Hcatb  = alloc((size_t)ROWS * C1 * 2);        // 8 MiB bf16
  size_t o_T4     = alloc((size_t)ROWS * F_ * 4);        // f32
  size_t o_T4b    = alloc((size_t)ROWS * F_ * 2);        // bf16
  size_t o_T6     = alloc((size_t)ROWS * F_ * 4);
  size_t o_Z0     = alloc((size_t)ROWS * L0_ * 4);       // f32
  size_t o_E      = alloc((size_t)ROWS * L0_ * 2);       // bf16
  size_t o_Xb     = alloc((size_t)ROWS * F_ * 2);        // bf16 X
  size_t o_Wsb    = alloc((size_t)8 * G_ * F_ * 2);      // Ws transposed bf16
  size_t o_We1b   = alloc((size_t)F_ * C1 * 2);
  size_t o_Wl1b   = alloc((size_t)F_ * L0_ * 2);
  size_t o_W0p    = alloc((size_t)L0_ * F_ * 2);
  size_t o_bias0  = alloc(L0_ * 4);

  int*   fill   = (int*)(ws + o_fill);
  float* stats  = (float*)(ws + o_stats);
  int*   flag   = (int*)(ws + o_flag);
  float* S      = (float*)(ws + o_S);
  int*   colbuf = (int*)(ws + o_colbuf);
  float* q      = (float*)(ws + o_q);
  float* v      = (float*)(ws + o_v);
  float* Wh     = (float*)(ws + o_Wh);
  unsigned short* Hcatb = (unsigned short*)(ws + o_Hcatb);
  float* T4     = (float*)(ws + o_T4);
  unsigned short* T4b   = (unsigned short*)(ws + o_T4b);
  float* T6     = (float*)(ws + o_T6);
  float* Z0     = (float*)(ws + o_Z0);
  unsigned short* E     = (unsigned short*)(ws + o_E);
  unsigned short* Xb    = (unsigned short*)(ws + o_Xb);
  unsigned short* Wsb   = (unsigned short*)(ws + o_Wsb);
  unsigned short* We1b  = (unsigned short*)(ws + o_We1b);
  unsigned short* Wl1b  = (unsigned short*)(ws + o_Wl1b);
  unsigned short* W0p   = (unsigned short*)(ws + o_W0p);
  float* bias0  = (float*)(ws + o_bias0);
  float* sum1 = stats,       *ssq1 = stats + 128;
  float* sum2 = stats + 256, *ssq2 = stats + 512;
  float* sum3 = stats + 768, *ssq3 = stats + 896;

  hipMemsetAsync(ws, 0, zero_bytes, stream);

  k_detect<<<512, 256, 0, stream>>>((const unsigned short*)X, flag);
  k_cvtw<<<4736, 256, 0, stream>>>(X, Ws, We1, Wl1, Xb, Wsb, We1b, Wl1b, flag);

  k_proj_qv<<<(64 * N_) / 4, 256, 0, stream>>>(X, Wq, Wv, q, v, flag);
  k_whm<<<dim3(ROWS / 16, 8), 64, 0, stream>>>(Xb, Wsb, Wh, S);

  k_scatter2<<<(16 * NE) / 256, 256, 0, stream>>>(A, fill, colbuf);
  k_attn2<<<16 * N_, 256, 0, stream>>>(q, v, Wh, S, fill, colbuf, Hcatb);

  k_mm1m<<<dim3(ROWS / 16, 2), 64, 0, stream>>>(Hcatb, We1b, X, T4, T4b, sum1, ssq1, flag);
  k_fold0<<<L0_, 128, 0, stream>>>(Wl0, sum1, ssq1, W0p, bias0, flag);
  k_lin0m<<<dim3(ROWS / 16, 4), 64, 0, stream>>>(T4b, W0p, bias0, Z0, sum2, ssq2);
  k_elu<<<(ROWS * L0_) / 256, 256, 0, stream>>>(Z0, E, sum2, ssq2);
  k_lin1m<<<dim3(ROWS / 16, 2), 64, 0, stream>>>(E, Wl1b, T4, sum1, ssq1, T6, sum3, ssq3);
  k_norm_out<<<(ROWS * F_) / 256, 256, 0, stream>>>(T6, d_out, sum3, ssq3, flag);

  (void)in_sizes; (void)n_in; (void)out_size; (void)ws_size;
}

// Round 9
// 236.553 us; speedup vs baseline: 1.1286x; 1.0453x over previous
//
#include <hip/hip_runtime.h>
#include <hip/hip_bf16.h>

#define B_    8
#define N_    1024
#define F_    128
#define G_    64
#define EC    2
#define NHD   4
#define NE    16384
#define L0_   256
#define ALPHA_ 0.5f
#define EPS_   1e-5f
#define SLOPE_ 0.01f
#define ROWS  (B_*N_)      // 8192
#define C1    (NHD*EC*G_)  // 512

typedef __attribute__((ext_vector_type(8))) short s8bf;   // 8 bf16 (4 VGPRs)
typedef __attribute__((ext_vector_type(4))) float f32x4;  // MFMA accumulator

__device__ __forceinline__ float ldv(const float* p, size_t i) { return p[i]; }
__device__ __forceinline__ float ldv(const __hip_bfloat16* p, size_t i) {
  unsigned short u = *(const unsigned short*)&p[i];
  return __uint_as_float((unsigned)u << 16);
}
__device__ __forceinline__ unsigned short f2b(float f) {   // RNE f32 -> bf16
  unsigned u = __float_as_uint(f);
  u = (u + 0x7FFFu + ((u >> 16) & 1u)) >> 16;
  return (unsigned short)u;
}
__device__ __forceinline__ float b2f(unsigned short u) {
  return __uint_as_float((unsigned)u << 16);
}

__device__ __forceinline__ float wmaxf(float v) {
#pragma unroll
  for (int o = 32; o; o >>= 1) v = fmaxf(v, __shfl_xor(v, o, 64));
  return v;
}
__device__ __forceinline__ float wsumf(float v) {
#pragma unroll
  for (int o = 32; o; o >>= 1) v += __shfl_xor(v, o, 64);
  return v;
}

// ---- dtype detector (proven round 2 — do not change logic) ----------------
__global__ void k_detect(const unsigned short* Xu, int* flag) {
  int idx = blockIdx.x * 256 + threadIdx.x;
  unsigned short u = Xu[idx];
  if ((u & 0x7F80u) == 0x7F80u) atomicOr(flag, 1);
}

// ---- bf16 conversion: X / Ws(transposed) / We1 / Wl1 / Wl0 ----------------
__device__ __forceinline__ unsigned short cvt_at(const void* p, size_t i, int isf) {
  return isf ? f2b(((const float*)p)[i]) : ((const unsigned short*)p)[i];
}
__global__ void k_cvtw(const void* X, const void* Ws, const void* We1, const void* Wl1,
                       const void* Wl0, unsigned short* Xb, unsigned short* Wsb,
                       unsigned short* We1b, unsigned short* Wl1b, unsigned short* Wl0b,
                       const int* flag) {
  int isf = *flag;
  int bid = blockIdx.x, t = threadIdx.x;
  if (bid < 4096) {                       // X: 8192*128
    int i = bid * 256 + t; Xb[i] = cvt_at(X, i, isf);
  } else if (bid < 4352) {                // We1: 128*512
    int i = (bid - 4096) * 256 + t; We1b[i] = cvt_at(We1, i, isf);
  } else if (bid < 4480) {                // Wl1: 128*256
    int i = (bid - 4352) * 256 + t; Wl1b[i] = cvt_at(Wl1, i, isf);
  } else if (bid < 4608) {                // Wl0: 256*128
    int i = (bid - 4480) * 256 + t; Wl0b[i] = cvt_at(Wl0, i, isf);
  } else {                                // Ws: [eh][f][g] -> Wsb [eh][g][f]
    int i = (bid - 4608) * 256 + t;       // 0..65535
    int eh = i >> 13, rem = i & 8191;
    int g = rem >> 7, f = rem & 127;
    Wsb[eh * 8192 + g * 128 + f] = cvt_at(Ws, (size_t)eh * 8192 + f * 64 + g, isf);
  }
}

// ---- q/v projections (f32-accurate, unchanged) ----------------------------
template <typename T>
__device__ __forceinline__ void proj_qv_body(const T* X, const T* Wq, const T* Wv,
                                             float* q, float* v) {
  int tid = threadIdx.x, lane = tid & 63, w = tid >> 6;
  int r = blockIdx.x * 4 + w;
  int n = r & (N_ - 1); int beh = r >> 10; int be = beh >> 2, h = beh & 3;
  int b = be >> 1, e = be & 1;
  const T* xr = X + ((size_t)(b * N_ + n)) * F_;
  const T* wq = Wq + (e * NHD + h) * F_;
  const T* wv = Wv + (e * NHD + h) * F_;
  float x0 = ldv(xr, lane), x1 = ldv(xr, lane + 64);
  float aq = x0 * ldv(wq, lane) + x1 * ldv(wq, lane + 64);
  float av = x0 * ldv(wv, lane) + x1 * ldv(wv, lane + 64);
  aq = wsumf(aq); av = wsumf(av);
  if (lane == 0) { q[r] = aq; v[r] = av; }
}
__global__ void k_proj_qv(const void* X, const void* Wq, const void* Wv,
                          float* q, float* v, const int* flag) {
  if (*flag) proj_qv_body<float>((const float*)X, (const float*)Wq, (const float*)Wv, q, v);
  else       proj_qv_body<__hip_bfloat16>((const __hip_bfloat16*)X, (const __hip_bfloat16*)Wq,
                                          (const __hip_bfloat16*)Wv, q, v);
}

// ---- MFMA core (bf16 A from memory), 16x64 tile per wave ------------------
template <int K>
__device__ __forceinline__ void mfma_core(const unsigned short* __restrict__ Ab,
                                          const unsigned short* __restrict__ Wb,
                                          int r0, int c0, f32x4* acc) {
  int lane = threadIdx.x & 63; int q = lane >> 4, c15 = lane & 15;
  constexpr int RS = K / 8;
  const s8bf* ap = (const s8bf*)Ab + (size_t)(r0 + c15) * RS + q;
  const s8bf* bp = (const s8bf*)Wb + (size_t)(c0 + c15) * RS + q;
#pragma unroll
  for (int ks = 0; ks < K / 32; ++ks) {
    s8bf a  = ap[ks * 4];
    s8bf b0 = bp[ks * 4];
    s8bf b1 = bp[16 * RS + ks * 4];
    s8bf b2 = bp[32 * RS + ks * 4];
    s8bf b3 = bp[48 * RS + ks * 4];
    acc[0] = __builtin_amdgcn_mfma_f32_16x16x32_bf16(a, b0, acc[0], 0, 0, 0);
    acc[1] = __builtin_amdgcn_mfma_f32_16x16x32_bf16(a, b1, acc[1], 0, 0, 0);
    acc[2] = __builtin_amdgcn_mfma_f32_16x16x32_bf16(a, b2, acc[2], 0, 0, 0);
    acc[3] = __builtin_amdgcn_mfma_f32_16x16x32_bf16(a, b3, acc[3], 0, 0, 0);
  }
}

// ---- MFMA core, A built in-register from f32 + BN(+ELU) transform ---------
template <int K, int MODE>   // MODE 1: bn(stats); 2: elu(bn(stats))
__device__ __forceinline__ void mfma_core_t(const float* __restrict__ Araw,
                                            const float* sum, const float* ssq,
                                            const unsigned short* __restrict__ Wb,
                                            int r0, int c0, f32x4* acc) {
  int lane = threadIdx.x & 63; int q = lane >> 4, c15 = lane & 15;
  constexpr int RS = K / 8;
  const float* ap = Araw + (size_t)(r0 + c15) * K + q * 8;
  const s8bf* bp = (const s8bf*)Wb + (size_t)(c0 + c15) * RS + q;
#pragma unroll
  for (int ks = 0; ks < K / 32; ++ks) {
    float av[8];
    *(float4*)&av[0] = *(const float4*)(ap + ks * 32);
    *(float4*)&av[4] = *(const float4*)(ap + ks * 32 + 4);
    s8bf a;
#pragma unroll
    for (int j = 0; j < 8; ++j) {
      int c = q * 8 + ks * 32 + j;
      float mean = sum[c] * (1.f / ROWS);
      float var = ssq[c] * (1.f / ROWS) - mean * mean;
      float y = (av[j] - mean) * rsqrtf(var + EPS_);
      if (MODE == 2) y = (y > 0.f) ? y : (expf(y) - 1.f);
      a[j] = (short)f2b(y);
    }
    s8bf b0 = bp[ks * 4];
    s8bf b1 = bp[16 * RS + ks * 4];
    s8bf b2 = bp[32 * RS + ks * 4];
    s8bf b3 = bp[48 * RS + ks * 4];
    acc[0] = __builtin_amdgcn_mfma_f32_16x16x32_bf16(a, b0, acc[0], 0, 0, 0);
    acc[1] = __builtin_amdgcn_mfma_f32_16x16x32_bf16(a, b1, acc[1], 0, 0, 0);
    acc[2] = __builtin_amdgcn_mfma_f32_16x16x32_bf16(a, b2, acc[2], 0, 0, 0);
    acc[3] = __builtin_amdgcn_mfma_f32_16x16x32_bf16(a, b3, acc[3], 0, 0, 0);
  }
}

// ---- Wh projection (MFMA) -> bf16 Wh + fused column-sum S (f32) -----------
__global__ __launch_bounds__(64) void k_whm(const unsigned short* Xb,
                                            const unsigned short* Wsb,
                                            unsigned short* Whb, float* S) {
  int r0 = blockIdx.x * 16; int eh = blockIdx.y;
  f32x4 acc[4] = {{0,0,0,0},{0,0,0,0},{0,0,0,0},{0,0,0,0}};
  mfma_core<128>(Xb, Wsb + eh * 8192, r0, 0, acc);
  int lane = threadIdx.x, q = lane >> 4, c15 = lane & 15;
  int b = r0 >> 10; int beh = b * 8 + eh;
  unsigned short* WhB = Whb + ((size_t)beh * N_ + (r0 & (N_ - 1))) * G_;
#pragma unroll
  for (int nc = 0; nc < 4; ++nc) {
    float s = 0.f;
#pragma unroll
    for (int i = 0; i < 4; ++i) {
      float o = acc[nc][i];
      WhB[(size_t)(q * 4 + i) * G_ + nc * 16 + c15] = f2b(o);
      s += o;
    }
    s += __shfl_xor(s, 16, 64); s += __shfl_xor(s, 32, 64);
    if (lane < 16) atomicAdd(&S[(size_t)beh * G_ + nc * 16 + lane], s);
  }
}

// ---- adjacency: direct fixed-capacity buckets -----------------------------
__global__ void k_scatter2(const int* A, int* fill, int* colbuf) {
  int idx = blockIdx.x * 256 + threadIdx.x;    // 16*NE
  int be = idx >> 14, i = idx & (NE - 1);
  int row = A[(size_t)(be * 2) * NE + i];
  int col = A[(size_t)(be * 2 + 1) * NE + i];
  int p = atomicAdd(&fill[be * N_ + row], 1);
  if (p < 64) colbuf[((size_t)(be * N_ + row)) * 64 + p] = col;
}

// ---- sparse attention v3: ONE WAVE per (be,n), all 4 heads ----------------
// No barriers, no cross-wave LDS; dedup once per wave; bf16 Wh gather.
__global__ __launch_bounds__(256) void k_attn3(const float* q, const float* v,
                                               const unsigned short* Whb,
                                               const float* S, const int* fill,
                                               const int* colbuf, unsigned short* Hcatb) {
  __shared__ int s_col[4][64];
  __shared__ int s_cnt[4][64];
  int tid = threadIdx.x, lane = tid & 63, w = tid >> 6;
  int p = blockIdx.x * 4 + w;
  int be = p >> 10, n = p & (N_ - 1);
  int b = be >> 1, e = be & 1;
  s_col[w][lane] = 0; s_cnt[w][lane] = 0;
  int L = fill[be * N_ + n];
  int Lc = (L > 64) ? 64 : L;
  int myc = (lane < Lc) ? colbuf[((size_t)(be * N_ + n)) * 64 + lane] : -1;
  int cct = 0, firstk = 64;
  for (int k = 0; k < Lc; ++k) {
    int ck = __shfl(myc, k, 64);
    if (myc >= 0 && ck == myc) { cct++; if (k < firstk) firstk = k; }
  }
  bool act = (lane < Lc) && (firstk == lane);
  unsigned long long mask = __ballot(act);
  int pos = __popcll(mask & ((1ull << lane) - 1ull));
  if (act) { s_col[w][pos] = myc; s_cnt[w][pos] = cct; }
  int Ld = __popcll(mask);
  // same-wave LDS write->read: DS ops execute in order per wave; no barrier
  int colc = s_col[w][lane];
  int cntc = s_cnt[w][lane];
  int eg = lane >> 4, g4 = (lane & 15) << 2;
  size_t outb = ((size_t)(b * N_ + n)) * C1 + e * G_ + g4;
  float fN = (float)(N_ - Ld);
#pragma unroll
  for (int h = 0; h < 4; ++h) {
    int beh = (be << 2) | h;
    float qn = q[beh * N_ + n];
    float sc = -1e30f;
    if (lane < Ld) {
      float t = qn * v[beh * N_ + colc] * (float)cntc;
      sc = (t >= 0.f) ? t : SLOPE_ * t;
    }
    float M = fmaxf(0.f, wmaxf(sc));
    float Ej = (lane < Ld) ? expf(sc - M) : 0.f;
    float sumE = wsumf(Ej);
    float em = expf(-M);
    float Z = fN * em + sumE;
    float wgt = (lane < Ld) ? (Ej - em) / Z : 0.f;
    float4 accv = make_float4(0.f, 0.f, 0.f, 0.f);
    if (eg == 0) {
      float4 s4 = *(const float4*)&S[(size_t)beh * G_ + g4];
      float sca = em / Z;
      accv.x = sca * s4.x; accv.y = sca * s4.y; accv.z = sca * s4.z; accv.w = sca * s4.w;
    }
    const unsigned short* WhB = Whb + (size_t)beh * N_ * G_;
    for (int k0 = 0; k0 < Ld; k0 += 4) {
      int kk = k0 + eg;
      float wk = __shfl(wgt, kk, 64);
      int ck = __shfl(colc, kk, 64);
      ushort4 xu = *(const ushort4*)&WhB[(size_t)ck * G_ + g4];
      accv.x += wk * b2f(xu.x); accv.y += wk * b2f(xu.y);
      accv.z += wk * b2f(xu.z); accv.w += wk * b2f(xu.w);
    }
    accv.x += __shfl_xor(accv.x, 16, 64); accv.y += __shfl_xor(accv.y, 16, 64);
    accv.z += __shfl_xor(accv.z, 16, 64); accv.w += __shfl_xor(accv.w, 16, 64);
    accv.x += __shfl_xor(accv.x, 32, 64); accv.y += __shfl_xor(accv.y, 32, 64);
    accv.z += __shfl_xor(accv.z, 32, 64); accv.w += __shfl_xor(accv.w, 32, 64);
    if (lane < 16) {
      ushort4 o;
      o.x = f2b(accv.x); o.y = f2b(accv.y); o.z = f2b(accv.z); o.w = f2b(accv.w);
      *(ushort4*)&Hcatb[outb + (size_t)h * (EC * G_)] = o;
    }
  }
}

// ---- mm1 (MFMA): T4 = 0.5*relu(Hcat @ We^T) + 0.5*X; f32 out + stats1 -----
template <typename TX>
__device__ __forceinline__ void mm1_ep(f32x4* acc, const TX* X, float* T4,
                                       float* sum1, float* ssq1, int r0, int c0) {
  int lane = threadIdx.x, q = lane >> 4, c15 = lane & 15;
#pragma unroll
  for (int nc = 0; nc < 4; ++nc) {
    int cc = c0 + nc * 16 + c15;
    float s = 0.f, s2 = 0.f;
#pragma unroll
    for (int i = 0; i < 4; ++i) {
      int rr = r0 + q * 4 + i;
      float o = fmaxf(acc[nc][i], 0.f);
      o = 0.5f * o + 0.5f * ldv(X, (size_t)rr * F_ + cc);
      T4[(size_t)rr * F_ + cc] = o;
      s += o; s2 += o * o;
    }
    s += __shfl_xor(s, 16, 64); s += __shfl_xor(s, 32, 64);
    s2 += __shfl_xor(s2, 16, 64); s2 += __shfl_xor(s2, 32, 64);
    if (lane < 16) {
      atomicAdd(&sum1[c0 + nc * 16 + lane], s);
      atomicAdd(&ssq1[c0 + nc * 16 + lane], s2);
    }
  }
}
__global__ __launch_bounds__(64) void k_mm1m(const unsigned short* Hcatb,
                                             const unsigned short* We1b, const void* X,
                                             float* T4, float* sum1, float* ssq1,
                                             const int* flag) {
  int r0 = blockIdx.x * 16, c0 = blockIdx.y * 64;
  f32x4 acc[4] = {{0,0,0,0},{0,0,0,0},{0,0,0,0},{0,0,0,0}};
  mfma_core<512>(Hcatb, We1b, r0, c0, acc);
  if (*flag) mm1_ep<float>(acc, (const float*)X, T4, sum1, ssq1, r0, c0);
  else       mm1_ep<__hip_bfloat16>(acc, (const __hip_bfloat16*)X, T4, sum1, ssq1, r0, c0);
}

// ---- lin0 (MFMA, fused bn1 on A): Z0 = bn1(T4) @ Wl0^T; stats2 ------------
__global__ __launch_bounds__(64) void k_lin0m(const float* T4, const float* sum1,
                                              const float* ssq1, const unsigned short* Wl0b,
                                              float* Z0, float* sum2, float* ssq2) {
  int r0 = blockIdx.x * 16, c0 = blockIdx.y * 64;
  f32x4 acc[4] = {{0,0,0,0},{0,0,0,0},{0,0,0,0},{0,0,0,0}};
  mfma_core_t<128, 1>(T4, sum1, ssq1, Wl0b, r0, c0, acc);
  int lane = threadIdx.x, q = lane >> 4, c15 = lane & 15;
#pragma unroll
  for (int nc = 0; nc < 4; ++nc) {
    int cc = c0 + nc * 16 + c15;
    float s = 0.f, s2 = 0.f;
#pragma unroll
    for (int i = 0; i < 4; ++i) {
      int rr = r0 + q * 4 + i;
      float o = acc[nc][i];
      Z0[(size_t)rr * L0_ + cc] = o;
      s += o; s2 += o * o;
    }
    s += __shfl_xor(s, 16, 64); s += __shfl_xor(s, 32, 64);
    s2 += __shfl_xor(s2, 16, 64); s2 += __shfl_xor(s2, 32, 64);
    if (lane < 16) {
      atomicAdd(&sum2[c0 + nc * 16 + lane], s);
      atomicAdd(&ssq2[c0 + nc * 16 + lane], s2);
    }
  }
}

// ---- lin1 (MFMA, fused elu(bn2) on A): T6 = bn1(T4) + A @ Wl1^T; stats3 ---
__global__ __launch_bounds__(64) void k_lin1m(const float* Z0, const float* sum2,
                                              const float* ssq2, const unsigned short* Wl1b,
                                              const float* T4, const float* sum1,
                                              const float* ssq1,
                                              float* T6, float* sum3, float* ssq3) {
  int r0 = blockIdx.x * 16, c0 = blockIdx.y * 64;
  f32x4 acc[4] = {{0,0,0,0},{0,0,0,0},{0,0,0,0},{0,0,0,0}};
  mfma_core_t<256, 2>(Z0, sum2, ssq2, Wl1b, r0, c0, acc);
  int lane = threadIdx.x, q = lane >> 4, c15 = lane & 15;
#pragma unroll
  for (int nc = 0; nc < 4; ++nc) {
    int cc = c0 + nc * 16 + c15;
    float mean = sum1[cc] * (1.f / ROWS);
    float var = ssq1[cc] * (1.f / ROWS) - mean * mean;
    float rs = rsqrtf(var + EPS_);
    float s = 0.f, s2 = 0.f;
#pragma unroll
    for (int i = 0; i < 4; ++i) {
      int rr = r0 + q * 4 + i;
      float o = acc[nc][i] + (T4[(size_t)rr * F_ + cc] - mean) * rs;
      T6[(size_t)rr * F_ + cc] = o;
      s += o; s2 += o * o;
    }
    s += __shfl_xor(s, 16, 64); s += __shfl_xor(s, 32, 64);
    s2 += __shfl_xor(s2, 16, 64); s2 += __shfl_xor(s2, 32, 64);
    if (lane < 16) {
      atomicAdd(&sum3[c0 + nc * 16 + lane], s);
      atomicAdd(&ssq3[c0 + nc * 16 + lane], s2);
    }
  }
}

__global__ void k_norm_out(const float* in, void* out, const float* sum, const float* ssq,
                           const int* flag) {
  int idx = blockIdx.x * 256 + threadIdx.x; int c = idx & (F_ - 1);
  float mean = sum[c] * (1.f / ROWS);
  float var = ssq[c] * (1.f / ROWS) - mean * mean;
  float y = (in[idx] - mean) * rsqrtf(var + EPS_);
  if (*flag) ((float*)out)[idx] = y;
  else       ((__hip_bfloat16*)out)[idx] = __float2bfloat16(y);
}

// ---------------------------------------------------------------------------
extern "C" void kernel_launch(void* const* d_in, const int* in_sizes, int n_in,
                              void* d_out, int out_size, void* d_ws, size_t ws_size,
                              hipStream_t stream) {
  const int* A    = (const int*)d_in[0];
  const void* X   = d_in[1];
  const void* Ws  = d_in[2];
  const void* Wq  = d_in[3];
  const void* Wv  = d_in[4];
  const void* We1 = d_in[5];
  const void* Wl0 = d_in[6];
  const void* Wl1 = d_in[7];

  char* ws = (char*)d_ws;
  size_t off = 0;
  auto alloc = [&](size_t bytes) { size_t o = off; off += (bytes + 255) & ~(size_t)255; return o; };
  size_t o_fill   = alloc(16 * N_ * 4);            // zeroed
  size_t o_stats  = alloc(1024 * 4);               // zeroed
  size_t o_flag   = alloc(256);                    // zeroed
  size_t o_S      = alloc((size_t)64 * G_ * 4);    // zeroed (atomic accum)
  size_t zero_bytes = off;
  size_t o_colbuf = alloc((size_t)16 * N_ * 64 * 4);     // 4 MiB
  size_t o_q      = alloc((size_t)64 * N_ * 4);
  size_t o_v      = alloc((size_t)64 * N_ * 4);
  size_t o_Whb    = alloc((size_t)64 * N_ * G_ * 2);     // 8 MiB bf16
  size_t o_Hcatb  = alloc((size_t)ROWS * C1 * 2);        // 8 MiB bf16
  size_t o_T4     = alloc((size_t)ROWS * F_ * 4);        // f32
  size_t o_T6     = alloc((size_t)ROWS * F_ * 4);
  size_t o_Z0     = alloc((size_t)ROWS * L0_ * 4);       // f32
  size_t o_Xb     = alloc((size_t)ROWS * F_ * 2);        // bf16 X
  size_t o_Wsb    = alloc((size_t)8 * G_ * F_ * 2);
  size_t o_We1b   = alloc((size_t)F_ * C1 * 2);
  size_t o_Wl1b   = alloc((size_t)F_ * L0_ * 2);
  size_t o_Wl0b   = alloc((size_t)L0_ * F_ * 2);

  int*   fill   = (int*)(ws + o_fill);
  float* stats  = (float*)(ws + o_stats);
  int*   flag   = (int*)(ws + o_flag);
  float* S      = (float*)(ws + o_S);
  int*   colbuf = (int*)(ws + o_colbuf);
  float* q      = (float*)(ws + o_q);
  float* v      = (float*)(ws + o_v);
  unsigned short* Whb   = (unsigned short*)(ws + o_Whb);
  unsigned short* Hcatb = (unsigned short*)(ws + o_Hcatb);
  float* T4     = (float*)(ws + o_T4);
  float* T6     = (float*)(ws + o_T6);
  float* Z0     = (float*)(ws + o_Z0);
  unsigned short* Xb    = (unsigned short*)(ws + o_Xb);
  unsigned short* Wsb   = (unsigned short*)(ws + o_Wsb);
  unsigned short* We1b  = (unsigned short*)(ws + o_We1b);
  unsigned short* Wl1b  = (unsigned short*)(ws + o_Wl1b);
  unsigned short* Wl0b  = (unsigned short*)(ws + o_Wl0b);
  float* sum1 = stats,       *ssq1 = stats + 128;
  float* sum2 = stats + 256, *ssq2 = stats + 512;
  float* sum3 = stats + 768, *ssq3 = stats + 896;

  hipMemsetAsync(ws, 0, zero_bytes, stream);

  k_detect<<<512, 256, 0, stream>>>((const unsigned short*)X, flag);
  k_cvtw<<<4864, 256, 0, stream>>>(X, Ws, We1, Wl1, Wl0, Xb, Wsb, We1b, Wl1b, Wl0b, flag);

  k_proj_qv<<<(64 * N_) / 4, 256, 0, stream>>>(X, Wq, Wv, q, v, flag);
  k_whm<<<dim3(ROWS / 16, 8), 64, 0, stream>>>(Xb, Wsb, Whb, S);

  k_scatter2<<<(16 * NE) / 256, 256, 0, stream>>>(A, fill, colbuf);
  k_attn3<<<(16 * N_) / 4, 256, 0, stream>>>(q, v, Whb, S, fill, colbuf, Hcatb);

  k_mm1m<<<dim3(ROWS / 16, 2), 64, 0, stream>>>(Hcatb, We1b, X, T4, sum1, ssq1, flag);
  k_lin0m<<<dim3(ROWS / 16, 4), 64, 0, stream>>>(T4, sum1, ssq1, Wl0b, Z0, sum2, ssq2);
  k_lin1m<<<dim3(ROWS / 16, 2), 64, 0, stream>>>(Z0, sum2, ssq2, Wl1b, T4, sum1, ssq1,
                                                 T6, sum3, ssq3);
  k_norm_out<<<(ROWS * F_) / 256, 256, 0, stream>>>(T6, d_out, sum3, ssq3, flag);

  (void)in_sizes; (void)n_in; (void)out_size; (void)ws_size;
}

// Round 10
// 225.875 us; speedup vs baseline: 1.1819x; 1.0473x over previous
//
#include <hip/hip_runtime.h>
#include <hip/hip_bf16.h>

#define B_    8
#define N_    1024
#define F_    128
#define G_    64
#define EC    2
#define NHD   4
#define NE    16384
#define L0_   256
#define ALPHA_ 0.5f
#define EPS_   1e-5f
#define SLOPE_ 0.01f
#define ROWS  (B_*N_)      // 8192
#define C1    (NHD*EC*G_)  // 512

typedef __attribute__((ext_vector_type(8))) short s8bf;   // 8 bf16 (4 VGPRs)
typedef __attribute__((ext_vector_type(4))) float f32x4;  // MFMA accumulator

__device__ __forceinline__ float ldv(const float* p, size_t i) { return p[i]; }
__device__ __forceinline__ float ldv(const __hip_bfloat16* p, size_t i) {
  unsigned short u = *(const unsigned short*)&p[i];
  return __uint_as_float((unsigned)u << 16);
}
__device__ __forceinline__ unsigned short f2b(float f) {   // RNE f32 -> bf16
  unsigned u = __float_as_uint(f);
  u = (u + 0x7FFFu + ((u >> 16) & 1u)) >> 16;
  return (unsigned short)u;
}
__device__ __forceinline__ float b2f(unsigned short u) {
  return __uint_as_float((unsigned)u << 16);
}

__device__ __forceinline__ float wmaxf(float v) {
#pragma unroll
  for (int o = 32; o; o >>= 1) v = fmaxf(v, __shfl_xor(v, o, 64));
  return v;
}
__device__ __forceinline__ float wsumf(float v) {
#pragma unroll
  for (int o = 32; o; o >>= 1) v += __shfl_xor(v, o, 64);
  return v;
}

// ---- prep: dtype detect (bid<512) + adjacency scatter (bid>=512) ----------
__global__ void k_prep(const unsigned short* Xu, int* flag,
                       const int* A, int* fill, int* colbuf) {
  int bid = blockIdx.x, tid = threadIdx.x;
  if (bid < 512) {                         // detect (proven round 2 — unchanged logic)
    int idx = bid * 256 + tid;
    unsigned short u = Xu[idx];
    if ((u & 0x7F80u) == 0x7F80u) atomicOr(flag, 1);
  } else {                                 // scatter: fixed-capacity row buckets
    int idx = (bid - 512) * 256 + tid;     // 16*NE
    int be = idx >> 14, i = idx & (NE - 1);
    int row = A[(size_t)(be * 2) * NE + i];
    int col = A[(size_t)(be * 2 + 1) * NE + i];
    int p = atomicAdd(&fill[be * N_ + row], 1);
    if (p < 64) colbuf[((size_t)(be * N_ + row)) * 64 + p] = col;
  }
}

// ---- cvt2: bf16 conversions (bid<4864) + q/v projections (bid>=4864) ------
__device__ __forceinline__ unsigned short cvt_at(const void* p, size_t i, int isf) {
  return isf ? f2b(((const float*)p)[i]) : ((const unsigned short*)p)[i];
}
template <typename T>
__device__ __forceinline__ void proj_qv_body(const T* X, const T* Wq, const T* Wv,
                                             float* q, float* v, int pb) {
  int tid = threadIdx.x, lane = tid & 63, w = tid >> 6;
  int r = pb * 4 + w;
  int n = r & (N_ - 1); int beh = r >> 10; int be = beh >> 2, h = beh & 3;
  int b = be >> 1, e = be & 1;
  const T* xr = X + ((size_t)(b * N_ + n)) * F_;
  const T* wq = Wq + (e * NHD + h) * F_;
  const T* wv = Wv + (e * NHD + h) * F_;
  float x0 = ldv(xr, lane), x1 = ldv(xr, lane + 64);
  float aq = x0 * ldv(wq, lane) + x1 * ldv(wq, lane + 64);
  float av = x0 * ldv(wv, lane) + x1 * ldv(wv, lane + 64);
  aq = wsumf(aq); av = wsumf(av);
  if (lane == 0) { q[r] = aq; v[r] = av; }
}
__global__ void k_cvt2(const void* X, const void* Ws, const void* We1, const void* Wl1,
                       const void* Wl0, const void* Wq, const void* Wv,
                       unsigned short* Xb, unsigned short* Wsb, unsigned short* We1b,
                       unsigned short* Wl1b, unsigned short* Wl0b,
                       float* q, float* v, const int* flag) {
  int isf = *flag;
  int bid = blockIdx.x, t = threadIdx.x;
  if (bid < 4096) {                       // X: 8192*128
    int i = bid * 256 + t; Xb[i] = cvt_at(X, i, isf);
  } else if (bid < 4352) {                // We1: 128*512
    int i = (bid - 4096) * 256 + t; We1b[i] = cvt_at(We1, i, isf);
  } else if (bid < 4480) {                // Wl1: 128*256
    int i = (bid - 4352) * 256 + t; Wl1b[i] = cvt_at(Wl1, i, isf);
  } else if (bid < 4608) {                // Wl0: 256*128
    int i = (bid - 4480) * 256 + t; Wl0b[i] = cvt_at(Wl0, i, isf);
  } else if (bid < 4864) {                // Ws: [eh][f][g] -> Wsb [eh][g][f]
    int i = (bid - 4608) * 256 + t;       // 0..65535
    int eh = i >> 13, rem = i & 8191;
    int g = rem >> 7, f = rem & 127;
    Wsb[eh * 8192 + g * 128 + f] = cvt_at(Ws, (size_t)eh * 8192 + f * 64 + g, isf);
  } else {                                // q/v projections
    int pb = bid - 4864;                  // 0..16383
    if (isf) proj_qv_body<float>((const float*)X, (const float*)Wq, (const float*)Wv, q, v, pb);
    else     proj_qv_body<__hip_bfloat16>((const __hip_bfloat16*)X, (const __hip_bfloat16*)Wq,
                                          (const __hip_bfloat16*)Wv, q, v, pb);
  }
}

// ---- MFMA core (bf16 A from memory), 16x64 tile per wave ------------------
template <int K>
__device__ __forceinline__ void mfma_core(const unsigned short* __restrict__ Ab,
                                          const unsigned short* __restrict__ Wb,
                                          int r0, int c0, f32x4* acc) {
  int lane = threadIdx.x & 63; int q = lane >> 4, c15 = lane & 15;
  constexpr int RS = K / 8;
  const s8bf* ap = (const s8bf*)Ab + (size_t)(r0 + c15) * RS + q;
  const s8bf* bp = (const s8bf*)Wb + (size_t)(c0 + c15) * RS + q;
#pragma unroll
  for (int ks = 0; ks < K / 32; ++ks) {
    s8bf a  = ap[ks * 4];
    s8bf b0 = bp[ks * 4];
    s8bf b1 = bp[16 * RS + ks * 4];
    s8bf b2 = bp[32 * RS + ks * 4];
    s8bf b3 = bp[48 * RS + ks * 4];
    acc[0] = __builtin_amdgcn_mfma_f32_16x16x32_bf16(a, b0, acc[0], 0, 0, 0);
    acc[1] = __builtin_amdgcn_mfma_f32_16x16x32_bf16(a, b1, acc[1], 0, 0, 0);
    acc[2] = __builtin_amdgcn_mfma_f32_16x16x32_bf16(a, b2, acc[2], 0, 0, 0);
    acc[3] = __builtin_amdgcn_mfma_f32_16x16x32_bf16(a, b3, acc[3], 0, 0, 0);
  }
}

// ---- MFMA core, A built in-register from f32 + BN(+ELU) transform ---------
template <int K, int MODE>   // MODE 1: bn(stats); 2: elu(bn(stats))
__device__ __forceinline__ void mfma_core_t(const float* __restrict__ Araw,
                                            const float* sum, const float* ssq,
                                            const unsigned short* __restrict__ Wb,
                                            int r0, int c0, f32x4* acc) {
  int lane = threadIdx.x & 63; int q = lane >> 4, c15 = lane & 15;
  constexpr int RS = K / 8;
  const float* ap = Araw + (size_t)(r0 + c15) * K + q * 8;
  const s8bf* bp = (const s8bf*)Wb + (size_t)(c0 + c15) * RS + q;
#pragma unroll
  for (int ks = 0; ks < K / 32; ++ks) {
    float av[8];
    *(float4*)&av[0] = *(const float4*)(ap + ks * 32);
    *(float4*)&av[4] = *(const float4*)(ap + ks * 32 + 4);
    s8bf a;
#pragma unroll
    for (int j = 0; j < 8; ++j) {
      int c = q * 8 + ks * 32 + j;
      float mean = sum[c] * (1.f / ROWS);
      float var = ssq[c] * (1.f / ROWS) - mean * mean;
      float y = (av[j] - mean) * rsqrtf(var + EPS_);
      if (MODE == 2) y = (y > 0.f) ? y : (expf(y) - 1.f);
      a[j] = (short)f2b(y);
    }
    s8bf b0 = bp[ks * 4];
    s8bf b1 = bp[16 * RS + ks * 4];
    s8bf b2 = bp[32 * RS + ks * 4];
    s8bf b3 = bp[48 * RS + ks * 4];
    acc[0] = __builtin_amdgcn_mfma_f32_16x16x32_bf16(a, b0, acc[0], 0, 0, 0);
    acc[1] = __builtin_amdgcn_mfma_f32_16x16x32_bf16(a, b1, acc[1], 0, 0, 0);
    acc[2] = __builtin_amdgcn_mfma_f32_16x16x32_bf16(a, b2, acc[2], 0, 0, 0);
    acc[3] = __builtin_amdgcn_mfma_f32_16x16x32_bf16(a, b3, acc[3], 0, 0, 0);
  }
}

// ---- Wh projection (MFMA, 4 tiles/block) -> bf16 Wh + column-sum S --------
__global__ __launch_bounds__(256) void k_whm(const unsigned short* Xb,
                                             const unsigned short* Wsb,
                                             unsigned short* Whb, float* S) {
  int w = threadIdx.x >> 6;
  int r0 = (blockIdx.x * 4 + w) * 16; int eh = blockIdx.y;
  f32x4 acc[4] = {{0,0,0,0},{0,0,0,0},{0,0,0,0},{0,0,0,0}};
  mfma_core<128>(Xb, Wsb + eh * 8192, r0, 0, acc);
  int lane = threadIdx.x & 63, q = lane >> 4, c15 = lane & 15;
  int b = r0 >> 10; int beh = b * 8 + eh;
  unsigned short* WhB = Whb + ((size_t)beh * N_ + (r0 & (N_ - 1))) * G_;
#pragma unroll
  for (int nc = 0; nc < 4; ++nc) {
    float s = 0.f;
#pragma unroll
    for (int i = 0; i < 4; ++i) {
      float o = acc[nc][i];
      WhB[(size_t)(q * 4 + i) * G_ + nc * 16 + c15] = f2b(o);
      s += o;
    }
    s += __shfl_xor(s, 16, 64); s += __shfl_xor(s, 32, 64);
    if (lane < 16) atomicAdd(&S[(size_t)beh * G_ + nc * 16 + lane], s);
  }
}

// ---- sparse attention v4: one wave per (be,n), XCD-aware be swizzle -------
// xcd = blockIdx&7 handles be in {2*xcd, 2*xcd+1}: per-XCD L2 working set
// = 2 be x 512 KB = 1 MB (fits 4 MB) -> HBM gather fetch ~8 MB instead of 60.
__global__ __launch_bounds__(256) void k_attn3(const float* q, const float* v,
                                               const unsigned short* Whb,
                                               const float* S, const int* fill,
                                               const int* colbuf, unsigned short* Hcatb) {
  int tid = threadIdx.x, lane = tid & 63, w = tid >> 6;
  int xcd = blockIdx.x & 7, j = blockIdx.x >> 3;
  int be = (xcd << 1) | (j & 1);
  int n = (j >> 1) * 4 + w;
  int b = be >> 1, e = be & 1;
  int L = fill[be * N_ + n];
  int Lc = (L > 64) ? 64 : L;
  int myc = (lane < Lc) ? colbuf[((size_t)(be * N_ + n)) * 64 + lane] : -1;
  int cct = 0, firstk = 64;
  for (int k = 0; k < Lc; ++k) {
    int ck = __shfl(myc, k, 64);
    if (myc >= 0 && ck == myc) { cct++; if (k < firstk) firstk = k; }
  }
  bool act = (lane < Lc) && (firstk == lane);
  unsigned long long mask = __ballot(act);
  int pos = __popcll(mask & ((1ull << lane) - 1ull));
  // compact (col,cnt) to low lanes via bpermute-free trick: write via shfl target
  // use LDS-free compaction: each active lane sends to lane 'pos' using ds_permute
  // simplest correct path: LDS per-wave scratch
  __shared__ int s_col[4][64];
  __shared__ int s_cnt[4][64];
  s_col[w][lane] = 0; s_cnt[w][lane] = 0;
  if (act) { s_col[w][pos] = myc; s_cnt[w][pos] = cct; }
  int Ld = __popcll(mask);
  int colc = s_col[w][lane];          // same-wave DS ordering: no barrier needed
  int cntc = s_cnt[w][lane];
  int eg = lane >> 4, g4 = (lane & 15) << 2;
  size_t outb = ((size_t)(b * N_ + n)) * C1 + e * G_ + g4;
  float fN = (float)(N_ - Ld);
#pragma unroll
  for (int h = 0; h < 4; ++h) {
    int beh = (be << 2) | h;
    float qn = q[beh * N_ + n];
    float sc = -1e30f;
    if (lane < Ld) {
      float t = qn * v[beh * N_ + colc] * (float)cntc;
      sc = (t >= 0.f) ? t : SLOPE_ * t;
    }
    float M = fmaxf(0.f, wmaxf(sc));
    float Ej = (lane < Ld) ? expf(sc - M) : 0.f;
    float sumE = wsumf(Ej);
    float em = expf(-M);
    float Z = fN * em + sumE;
    float wgt = (lane < Ld) ? (Ej - em) / Z : 0.f;
    float4 accv = make_float4(0.f, 0.f, 0.f, 0.f);
    if (eg == 0) {
      float4 s4 = *(const float4*)&S[(size_t)beh * G_ + g4];
      float sca = em / Z;
      accv.x = sca * s4.x; accv.y = sca * s4.y; accv.z = sca * s4.z; accv.w = sca * s4.w;
    }
    const unsigned short* WhB = Whb + (size_t)beh * N_ * G_;
    for (int k0 = 0; k0 < Ld; k0 += 4) {
      int kk = k0 + eg;
      float wk = __shfl(wgt, kk, 64);
      int ck = __shfl(colc, kk, 64);
      ushort4 xu = *(const ushort4*)&WhB[(size_t)ck * G_ + g4];
      accv.x += wk * b2f(xu.x); accv.y += wk * b2f(xu.y);
      accv.z += wk * b2f(xu.z); accv.w += wk * b2f(xu.w);
    }
    accv.x += __shfl_xor(accv.x, 16, 64); accv.y += __shfl_xor(accv.y, 16, 64);
    accv.z += __shfl_xor(accv.z, 16, 64); accv.w += __shfl_xor(accv.w, 16, 64);
    accv.x += __shfl_xor(accv.x, 32, 64); accv.y += __shfl_xor(accv.y, 32, 64);
    accv.z += __shfl_xor(accv.z, 32, 64); accv.w += __shfl_xor(accv.w, 32, 64);
    if (lane < 16) {
      ushort4 o;
      o.x = f2b(accv.x); o.y = f2b(accv.y); o.z = f2b(accv.z); o.w = f2b(accv.w);
      *(ushort4*)&Hcatb[outb + (size_t)h * (EC * G_)] = o;
    }
  }
}

// ---- mm1 (MFMA, 4 tiles/block): T4 = 0.5*relu(Hcat@We^T)+0.5*X; stats1 ----
template <typename TX>
__device__ __forceinline__ void mm1_ep(f32x4* acc, const TX* X, float* T4,
                                       float* sum1, float* ssq1, int r0, int c0) {
  int lane = threadIdx.x & 63, q = lane >> 4, c15 = lane & 15;
#pragma unroll
  for (int nc = 0; nc < 4; ++nc) {
    int cc = c0 + nc * 16 + c15;
    float s = 0.f, s2 = 0.f;
#pragma unroll
    for (int i = 0; i < 4; ++i) {
      int rr = r0 + q * 4 + i;
      float o = fmaxf(acc[nc][i], 0.f);
      o = 0.5f * o + 0.5f * ldv(X, (size_t)rr * F_ + cc);
      T4[(size_t)rr * F_ + cc] = o;
      s += o; s2 += o * o;
    }
    s += __shfl_xor(s, 16, 64); s += __shfl_xor(s, 32, 64);
    s2 += __shfl_xor(s2, 16, 64); s2 += __shfl_xor(s2, 32, 64);
    if (lane < 16) {
      atomicAdd(&sum1[c0 + nc * 16 + lane], s);
      atomicAdd(&ssq1[c0 + nc * 16 + lane], s2);
    }
  }
}
__global__ __launch_bounds__(256) void k_mm1m(const unsigned short* Hcatb,
                                              const unsigned short* We1b, const void* X,
                                              float* T4, float* sum1, float* ssq1,
                                              const int* flag) {
  int w = threadIdx.x >> 6;
  int r0 = (blockIdx.x * 4 + w) * 16, c0 = blockIdx.y * 64;
  f32x4 acc[4] = {{0,0,0,0},{0,0,0,0},{0,0,0,0},{0,0,0,0}};
  mfma_core<512>(Hcatb, We1b, r0, c0, acc);
  if (*flag) mm1_ep<float>(acc, (const float*)X, T4, sum1, ssq1, r0, c0);
  else       mm1_ep<__hip_bfloat16>(acc, (const __hip_bfloat16*)X, T4, sum1, ssq1, r0, c0);
}

// ---- lin0 (MFMA, fused bn1 on A, 4 tiles/block): Z0; stats2 ---------------
__global__ __launch_bounds__(256) void k_lin0m(const float* T4, const float* sum1,
                                               const float* ssq1, const unsigned short* Wl0b,
                                               float* Z0, float* sum2, float* ssq2) {
  int w = threadIdx.x >> 6;
  int r0 = (blockIdx.x * 4 + w) * 16, c0 = blockIdx.y * 64;
  f32x4 acc[4] = {{0,0,0,0},{0,0,0,0},{0,0,0,0},{0,0,0,0}};
  mfma_core_t<128, 1>(T4, sum1, ssq1, Wl0b, r0, c0, acc);
  int lane = threadIdx.x & 63, q = lane >> 4, c15 = lane & 15;
#pragma unroll
  for (int nc = 0; nc < 4; ++nc) {
    int cc = c0 + nc * 16 + c15;
    float s = 0.f, s2 = 0.f;
#pragma unroll
    for (int i = 0; i < 4; ++i) {
      int rr = r0 + q * 4 + i;
      float o = acc[nc][i];
      Z0[(size_t)rr * L0_ + cc] = o;
      s += o; s2 += o * o;
    }
    s += __shfl_xor(s, 16, 64); s += __shfl_xor(s, 32, 64);
    s2 += __shfl_xor(s2, 16, 64); s2 += __shfl_xor(s2, 32, 64);
    if (lane < 16) {
      atomicAdd(&sum2[c0 + nc * 16 + lane], s);
      atomicAdd(&ssq2[c0 + nc * 16 + lane], s2);
    }
  }
}

// ---- lin1 (MFMA, fused elu(bn2) on A, 4 tiles/block): T6; stats3 ----------
__global__ __launch_bounds__(256) void k_lin1m(const float* Z0, const float* sum2,
                                               const float* ssq2, const unsigned short* Wl1b,
                                               const float* T4, const float* sum1,
                                               const float* ssq1,
                                               float* T6, float* sum3, float* ssq3) {
  int w = threadIdx.x >> 6;
  int r0 = (blockIdx.x * 4 + w) * 16, c0 = blockIdx.y * 64;
  f32x4 acc[4] = {{0,0,0,0},{0,0,0,0},{0,0,0,0},{0,0,0,0}};
  mfma_core_t<256, 2>(Z0, sum2, ssq2, Wl1b, r0, c0, acc);
  int lane = threadIdx.x & 63, q = lane >> 4, c15 = lane & 15;
#pragma unroll
  for (int nc = 0; nc < 4; ++nc) {
    int cc = c0 + nc * 16 + c15;
    float mean = sum1[cc] * (1.f / ROWS);
    float var = ssq1[cc] * (1.f / ROWS) - mean * mean;
    float rs = rsqrtf(var + EPS_);
    float s = 0.f, s2 = 0.f;
#pragma unroll
    for (int i = 0; i < 4; ++i) {
      int rr = r0 + q * 4 + i;
      float o = acc[nc][i] + (T4[(size_t)rr * F_ + cc] - mean) * rs;
      T6[(size_t)rr * F_ + cc] = o;
      s += o; s2 += o * o;
    }
    s += __shfl_xor(s, 16, 64); s += __shfl_xor(s, 32, 64);
    s2 += __shfl_xor(s2, 16, 64); s2 += __shfl_xor(s2, 32, 64);
    if (lane < 16) {
      atomicAdd(&sum3[c0 + nc * 16 + lane], s);
      atomicAdd(&ssq3[c0 + nc * 16 + lane], s2);
    }
  }
}

__global__ void k_norm_out(const float* in, void* out, const float* sum, const float* ssq,
                           const int* flag) {
  int idx = blockIdx.x * 256 + threadIdx.x; int c = idx & (F_ - 1);
  float mean = sum[c] * (1.f / ROWS);
  float var = ssq[c] * (1.f / ROWS) - mean * mean;
  float y = (in[idx] - mean) * rsqrtf(var + EPS_);
  if (*flag) ((float*)out)[idx] = y;
  else       ((__hip_bfloat16*)out)[idx] = __float2bfloat16(y);
}

// ---------------------------------------------------------------------------
extern "C" void kernel_launch(void* const* d_in, const int* in_sizes, int n_in,
                              void* d_out, int out_size, void* d_ws, size_t ws_size,
                              hipStream_t stream) {
  const int* A    = (const int*)d_in[0];
  const void* X   = d_in[1];
  const void* Ws  = d_in[2];
  const void* Wq  = d_in[3];
  const void* Wv  = d_in[4];
  const void* We1 = d_in[5];
  const void* Wl0 = d_in[6];
  const void* Wl1 = d_in[7];

  char* ws = (char*)d_ws;
  size_t off = 0;
  auto alloc = [&](size_t bytes) { size_t o = off; off += (bytes + 255) & ~(size_t)255; return o; };
  size_t o_fill   = alloc(16 * N_ * 4);            // zeroed
  size_t o_stats  = alloc(1024 * 4);               // zeroed
  size_t o_flag   = alloc(256);                    // zeroed
  size_t o_S      = alloc((size_t)64 * G_ * 4);    // zeroed (atomic accum)
  size_t zero_bytes = off;
  size_t o_colbuf = alloc((size_t)16 * N_ * 64 * 4);     // 4 MiB
  size_t o_q      = alloc((size_t)64 * N_ * 4);
  size_t o_v      = alloc((size_t)64 * N_ * 4);
  size_t o_Whb    = alloc((size_t)64 * N_ * G_ * 2);     // 8 MiB bf16
  size_t o_Hcatb  = alloc((size_t)ROWS * C1 * 2);        // 8 MiB bf16
  size_t o_T4     = alloc((size_t)ROWS * F_ * 4);        // f32
  size_t o_T6     = alloc((size_t)ROWS * F_ * 4);
  size_t o_Z0     = alloc((size_t)ROWS * L0_ * 4);       // f32
  size_t o_Xb     = alloc((size_t)ROWS * F_ * 2);        // bf16 X
  size_t o_Wsb    = alloc((size_t)8 * G_ * F_ * 2);
  size_t o_We1b   = alloc((size_t)F_ * C1 * 2);
  size_t o_Wl1b   = alloc((size_t)F_ * L0_ * 2);
  size_t o_Wl0b   = alloc((size_t)L0_ * F_ * 2);

  int*   fill   = (int*)(ws + o_fill);
  float* stats  = (float*)(ws + o_stats);
  int*   flag   = (int*)(ws + o_flag);
  float* S      = (float*)(ws + o_S);
  int*   colbuf = (int*)(ws + o_colbuf);
  float* q      = (float*)(ws + o_q);
  float* v      = (float*)(ws + o_v);
  unsigned short* Whb   = (unsigned short*)(ws + o_Whb);
  unsigned short* Hcatb = (unsigned short*)(ws + o_Hcatb);
  float* T4     = (float*)(ws + o_T4);
  float* T6     = (float*)(ws + o_T6);
  float* Z0     = (float*)(ws + o_Z0);
  unsigned short* Xb    = (unsigned short*)(ws + o_Xb);
  unsigned short* Wsb   = (unsigned short*)(ws + o_Wsb);
  unsigned short* We1b  = (unsigned short*)(ws + o_We1b);
  unsigned short* Wl1b  = (unsigned short*)(ws + o_Wl1b);
  unsigned short* Wl0b  = (unsigned short*)(ws + o_Wl0b);
  float* sum1 = stats,       *ssq1 = stats + 128;
  float* sum2 = stats + 256, *ssq2 = stats + 512;
  float* sum3 = stats + 768, *ssq3 = stats + 896;

  hipMemsetAsync(ws, 0, zero_bytes, stream);

  k_prep<<<1536, 256, 0, stream>>>((const unsigned short*)X, flag, A, fill, colbuf);
  k_cvt2<<<4864 + 16384, 256, 0, stream>>>(X, Ws, We1, Wl1, Wl0, Wq, Wv,
                                           Xb, Wsb, We1b, Wl1b, Wl0b, q, v, flag);
  k_whm<<<dim3(ROWS / 64, 8), 256, 0, stream>>>(Xb, Wsb, Whb, S);
  k_attn3<<<(16 * N_) / 4, 256, 0, stream>>>(q, v, Whb, S, fill, colbuf, Hcatb);
  k_mm1m<<<dim3(ROWS / 64, 2), 256, 0, stream>>>(Hcatb, We1b, X, T4, sum1, ssq1, flag);
  k_lin0m<<<dim3(ROWS / 64, 4), 256, 0, stream>>>(T4, sum1, ssq1, Wl0b, Z0, sum2, ssq2);
  k_lin1m<<<dim3(ROWS / 64, 2), 256, 0, stream>>>(Z0, sum2, ssq2, Wl1b, T4, sum1, ssq1,
                                                  T6, sum3, ssq3);
  k_norm_out<<<(ROWS * F_) / 256, 256, 0, stream>>>(T6, d_out, sum3, ssq3, flag);

  (void)in_sizes; (void)n_in; (void)out_size; (void)ws_size;
}

// Round 11
// 212.417 us; speedup vs baseline: 1.2568x; 1.0634x over previous
//
#include <hip/hip_runtime.h>
#include <hip/hip_bf16.h>

#define B_    8
#define N_    1024
#define F_    128
#define G_    64
#define EC    2
#define NHD   4
#define NE    16384
#define L0_   256
#define ALPHA_ 0.5f
#define EPS_   1e-5f
#define SLOPE_ 0.01f
#define ROWS  (B_*N_)      // 8192
#define C1    (NHD*EC*G_)  // 512

typedef __attribute__((ext_vector_type(8))) short s8bf;   // 8 bf16 (4 VGPRs)
typedef __attribute__((ext_vector_type(4))) float f32x4;  // MFMA accumulator

__device__ __forceinline__ float ldv(const float* p, size_t i) { return p[i]; }
__device__ __forceinline__ float ldv(const __hip_bfloat16* p, size_t i) {
  unsigned short u = *(const unsigned short*)&p[i];
  return __uint_as_float((unsigned)u << 16);
}
__device__ __forceinline__ unsigned short f2b(float f) {   // RNE f32 -> bf16
  unsigned u = __float_as_uint(f);
  u = (u + 0x7FFFu + ((u >> 16) & 1u)) >> 16;
  return (unsigned short)u;
}
__device__ __forceinline__ float b2f(unsigned short u) {
  return __uint_as_float((unsigned)u << 16);
}

__device__ __forceinline__ float wmaxf(float v) {
#pragma unroll
  for (int o = 32; o; o >>= 1) v = fmaxf(v, __shfl_xor(v, o, 64));
  return v;
}
__device__ __forceinline__ float wsumf(float v) {
#pragma unroll
  for (int o = 32; o; o >>= 1) v += __shfl_xor(v, o, 64);
  return v;
}

// ---- prep: dtype detect (bid<512) + adjacency scatter (bid>=512) ----------
__global__ void k_prep(const unsigned short* Xu, int* flag,
                       const int* A, int* fill, int* colbuf) {
  int bid = blockIdx.x, tid = threadIdx.x;
  if (bid < 512) {                         // detect (proven round 2 — unchanged logic)
    int idx = bid * 256 + tid;
    unsigned short u = Xu[idx];
    if ((u & 0x7F80u) == 0x7F80u) atomicOr(flag, 1);
  } else {                                 // scatter: fixed-capacity row buckets
    int idx = (bid - 512) * 256 + tid;     // 16*NE
    int be = idx >> 14, i = idx & (NE - 1);
    int row = A[(size_t)(be * 2) * NE + i];
    int col = A[(size_t)(be * 2 + 1) * NE + i];
    int p = atomicAdd(&fill[be * N_ + row], 1);
    if (p < 64) colbuf[((size_t)(be * N_ + row)) * 64 + p] = col;
  }
}

// ---- cvt2: weight conversions + 16-lane-group q/v projections -------------
__device__ __forceinline__ unsigned short cvt_at(const void* p, size_t i, int isf) {
  return isf ? f2b(((const float*)p)[i]) : ((const unsigned short*)p)[i];
}
template <typename T>
__device__ __forceinline__ void proj_qv16(const T* X, const T* Wq, const T* Wv,
                                          float* q, float* v, int pb) {
  int tid = threadIdx.x, lane = tid & 63, w = tid >> 6;
  int sub = lane >> 4, fl = lane & 15;
  int r = pb * 16 + w * 4 + sub;
  int n = r & (N_ - 1); int beh = r >> 10; int be = beh >> 2, h = beh & 3;
  int b = be >> 1, e = be & 1;
  const T* xr = X + (size_t)(b * N_ + n) * F_ + fl * 8;
  const T* wq = Wq + (e * NHD + h) * F_ + fl * 8;
  const T* wv = Wv + (e * NHD + h) * F_ + fl * 8;
  float dq = 0.f, dv = 0.f;
#pragma unroll
  for (int j = 0; j < 8; ++j) {
    float x = ldv(xr, j);
    dq += x * ldv(wq, j); dv += x * ldv(wv, j);
  }
#pragma unroll
  for (int o = 1; o < 16; o <<= 1) {
    dq += __shfl_xor(dq, o, 64); dv += __shfl_xor(dv, o, 64);
  }
  if (fl == 0) { q[r] = dq; v[r] = dv; }
}
__global__ void k_cvt2(const void* X, const void* Ws, const void* We1, const void* Wl1,
                       const void* Wl0, const void* Wq, const void* Wv,
                       unsigned short* Wsb, unsigned short* We1b,
                       unsigned short* Wl1b, unsigned short* Wl0b,
                       float* q, float* v, const int* flag) {
  int isf = *flag;
  int bid = blockIdx.x, t = threadIdx.x;
  if (bid < 256) {                        // We1: 128*512
    int i = bid * 256 + t; We1b[i] = cvt_at(We1, i, isf);
  } else if (bid < 384) {                 // Wl1: 128*256
    int i = (bid - 256) * 256 + t; Wl1b[i] = cvt_at(Wl1, i, isf);
  } else if (bid < 512) {                 // Wl0: 256*128
    int i = (bid - 384) * 256 + t; Wl0b[i] = cvt_at(Wl0, i, isf);
  } else if (bid < 768) {                 // Ws: [eh][f][g] -> Wsb [eh][g][f]
    int i = (bid - 512) * 256 + t;        // 0..65535
    int eh = i >> 13, rem = i & 8191;
    int g = rem >> 7, f = rem & 127;
    Wsb[eh * 8192 + g * 128 + f] = cvt_at(Ws, (size_t)eh * 8192 + f * 64 + g, isf);
  } else {                                // q/v projections: 4096 blocks, 16 r each
    int pb = bid - 768;
    if (isf) proj_qv16<float>((const float*)X, (const float*)Wq, (const float*)Wv, q, v, pb);
    else     proj_qv16<__hip_bfloat16>((const __hip_bfloat16*)X, (const __hip_bfloat16*)Wq,
                                       (const __hip_bfloat16*)Wv, q, v, pb);
  }
}

// ---- unified MFMA core: 16xNC*16 tile per wave; A bf16-direct or f32+BN ---
template <int K, int NC, int MODE, typename TA>
__device__ __forceinline__ void mfma_core_u(const TA* __restrict__ Araw,
                                            const float* sum, const float* ssq,
                                            const unsigned short* __restrict__ Wb,
                                            int r0, int c0, f32x4* acc) {
  int lane = threadIdx.x & 63; int q = lane >> 4, c15 = lane & 15;
  constexpr int RS = K / 8;
  const s8bf* bp = (const s8bf*)Wb + (size_t)(c0 + c15) * RS + q;
#pragma unroll
  for (int ks = 0; ks < K / 32; ++ks) {
    s8bf a;
    if constexpr (sizeof(TA) == 2) {
      const s8bf* ap = (const s8bf*)Araw + (size_t)(r0 + c15) * RS + q;
      a = ap[ks * 4];
    } else {
      const float* ap = (const float*)Araw + (size_t)(r0 + c15) * K + q * 8 + ks * 32;
      float av[8];
      *(float4*)&av[0] = *(const float4*)ap;
      *(float4*)&av[4] = *(const float4*)(ap + 4);
#pragma unroll
      for (int j = 0; j < 8; ++j) {
        float y = av[j];
        if (MODE) {
          int c = q * 8 + ks * 32 + j;
          float mean = sum[c] * (1.f / ROWS);
          float var = ssq[c] * (1.f / ROWS) - mean * mean;
          y = (y - mean) * rsqrtf(var + EPS_);
          if (MODE == 2) y = (y > 0.f) ? y : (expf(y) - 1.f);
        }
        a[j] = (short)f2b(y);
      }
    }
#pragma unroll
    for (int nc = 0; nc < NC; ++nc) {
      s8bf b = bp[(size_t)nc * 16 * RS + ks * 4];
      acc[nc] = __builtin_amdgcn_mfma_f32_16x16x32_bf16(a, b, acc[nc], 0, 0, 0);
    }
  }
}

// ---- Wh projection (MFMA, reads X directly) -> bf16 Wh + column-sum S -----
__global__ __launch_bounds__(256) void k_whm(const void* X, const unsigned short* Wsb,
                                             unsigned short* Whb, float* S,
                                             const int* flag) {
  int w = threadIdx.x >> 6;
  int r0 = (blockIdx.x * 4 + w) * 16; int eh = blockIdx.y;
  f32x4 acc[4] = {{0,0,0,0},{0,0,0,0},{0,0,0,0},{0,0,0,0}};
  if (*flag)
    mfma_core_u<128, 4, 0, float>((const float*)X, nullptr, nullptr,
                                  Wsb + eh * 8192, r0, 0, acc);
  else
    mfma_core_u<128, 4, 0, unsigned short>((const unsigned short*)X, nullptr, nullptr,
                                           Wsb + eh * 8192, r0, 0, acc);
  int lane = threadIdx.x & 63, q = lane >> 4, c15 = lane & 15;
  int b = r0 >> 10; int beh = b * 8 + eh;
  unsigned short* WhB = Whb + ((size_t)beh * N_ + (r0 & (N_ - 1))) * G_;
#pragma unroll
  for (int nc = 0; nc < 4; ++nc) {
    float s = 0.f;
#pragma unroll
    for (int i = 0; i < 4; ++i) {
      float o = acc[nc][i];
      WhB[(size_t)(q * 4 + i) * G_ + nc * 16 + c15] = f2b(o);
      s += o;
    }
    s += __shfl_xor(s, 16, 64); s += __shfl_xor(s, 32, 64);
    if (lane < 16) atomicAdd(&S[(size_t)beh * G_ + nc * 16 + lane], s);
  }
}

// ---- sparse attention v4 (round-10, passing — unchanged) ------------------
__global__ __launch_bounds__(256) void k_attn3(const float* q, const float* v,
                                               const unsigned short* Whb,
                                               const float* S, const int* fill,
                                               const int* colbuf, unsigned short* Hcatb) {
  int tid = threadIdx.x, lane = tid & 63, w = tid >> 6;
  int xcd = blockIdx.x & 7, j = blockIdx.x >> 3;
  int be = (xcd << 1) | (j & 1);
  int n = (j >> 1) * 4 + w;
  int b = be >> 1, e = be & 1;
  int L = fill[be * N_ + n];
  int Lc = (L > 64) ? 64 : L;
  int myc = (lane < Lc) ? colbuf[((size_t)(be * N_ + n)) * 64 + lane] : -1;
  int cct = 0, firstk = 64;
  for (int k = 0; k < Lc; ++k) {
    int ck = __shfl(myc, k, 64);
    if (myc >= 0 && ck == myc) { cct++; if (k < firstk) firstk = k; }
  }
  bool act = (lane < Lc) && (firstk == lane);
  unsigned long long mask = __ballot(act);
  int pos = __popcll(mask & ((1ull << lane) - 1ull));
  __shared__ int s_col[4][64];
  __shared__ int s_cnt[4][64];
  s_col[w][lane] = 0; s_cnt[w][lane] = 0;
  if (act) { s_col[w][pos] = myc; s_cnt[w][pos] = cct; }
  int Ld = __popcll(mask);
  int colc = s_col[w][lane];          // same-wave DS ordering: no barrier needed
  int cntc = s_cnt[w][lane];
  int eg = lane >> 4, g4 = (lane & 15) << 2;
  size_t outb = ((size_t)(b * N_ + n)) * C1 + e * G_ + g4;
  float fN = (float)(N_ - Ld);
#pragma unroll
  for (int h = 0; h < 4; ++h) {
    int beh = (be << 2) | h;
    float qn = q[beh * N_ + n];
    float sc = -1e30f;
    if (lane < Ld) {
      float t = qn * v[beh * N_ + colc] * (float)cntc;
      sc = (t >= 0.f) ? t : SLOPE_ * t;
    }
    float M = fmaxf(0.f, wmaxf(sc));
    float Ej = (lane < Ld) ? expf(sc - M) : 0.f;
    float sumE = wsumf(Ej);
    float em = expf(-M);
    float Z = fN * em + sumE;
    float wgt = (lane < Ld) ? (Ej - em) / Z : 0.f;
    float4 accv = make_float4(0.f, 0.f, 0.f, 0.f);
    if (eg == 0) {
      float4 s4 = *(const float4*)&S[(size_t)beh * G_ + g4];
      float sca = em / Z;
      accv.x = sca * s4.x; accv.y = sca * s4.y; accv.z = sca * s4.z; accv.w = sca * s4.w;
    }
    const unsigned short* WhB = Whb + (size_t)beh * N_ * G_;
    for (int k0 = 0; k0 < Ld; k0 += 4) {
      int kk = k0 + eg;
      float wk = __shfl(wgt, kk, 64);
      int ck = __shfl(colc, kk, 64);
      ushort4 xu = *(const ushort4*)&WhB[(size_t)ck * G_ + g4];
      accv.x += wk * b2f(xu.x); accv.y += wk * b2f(xu.y);
      accv.z += wk * b2f(xu.z); accv.w += wk * b2f(xu.w);
    }
    accv.x += __shfl_xor(accv.x, 16, 64); accv.y += __shfl_xor(accv.y, 16, 64);
    accv.z += __shfl_xor(accv.z, 16, 64); accv.w += __shfl_xor(accv.w, 16, 64);
    accv.x += __shfl_xor(accv.x, 32, 64); accv.y += __shfl_xor(accv.y, 32, 64);
    accv.z += __shfl_xor(accv.z, 32, 64); accv.w += __shfl_xor(accv.w, 32, 64);
    if (lane < 16) {
      ushort4 o;
      o.x = f2b(accv.x); o.y = f2b(accv.y); o.z = f2b(accv.z); o.w = f2b(accv.w);
      *(ushort4*)&Hcatb[outb + (size_t)h * (EC * G_)] = o;
    }
  }
}

// ---- mm1 (MFMA 16x32 tiles, 2048 waves): T4 = 0.5*relu(.)+0.5*X; stats1 ---
template <typename TX>
__device__ __forceinline__ void mm1_ep(f32x4* acc, const TX* X, float* T4,
                                       float* sum1, float* ssq1, int r0, int c0) {
  int lane = threadIdx.x & 63, q = lane >> 4, c15 = lane & 15;
#pragma unroll
  for (int nc = 0; nc < 2; ++nc) {
    int cc = c0 + nc * 16 + c15;
    float s = 0.f, s2 = 0.f;
#pragma unroll
    for (int i = 0; i < 4; ++i) {
      int rr = r0 + q * 4 + i;
      float o = fmaxf(acc[nc][i], 0.f);
      o = 0.5f * o + 0.5f * ldv(X, (size_t)rr * F_ + cc);
      T4[(size_t)rr * F_ + cc] = o;
      s += o; s2 += o * o;
    }
    s += __shfl_xor(s, 16, 64); s += __shfl_xor(s, 32, 64);
    s2 += __shfl_xor(s2, 16, 64); s2 += __shfl_xor(s2, 32, 64);
    if (lane < 16) {
      atomicAdd(&sum1[c0 + nc * 16 + lane], s);
      atomicAdd(&ssq1[c0 + nc * 16 + lane], s2);
    }
  }
}
__global__ __launch_bounds__(256) void k_mm1m(const unsigned short* Hcatb,
                                              const unsigned short* We1b, const void* X,
                                              float* T4, float* sum1, float* ssq1,
                                              const int* flag) {
  int w = threadIdx.x >> 6;
  int tile = blockIdx.x * 4 + w;                 // 2048 tiles
  int r0 = (tile >> 2) * 16, c0 = (tile & 3) * 32;
  f32x4 acc[2] = {{0,0,0,0},{0,0,0,0}};
  mfma_core_u<512, 2, 0, unsigned short>(Hcatb, nullptr, nullptr, We1b, r0, c0, acc);
  if (*flag) mm1_ep<float>(acc, (const float*)X, T4, sum1, ssq1, r0, c0);
  else       mm1_ep<__hip_bfloat16>(acc, (const __hip_bfloat16*)X, T4, sum1, ssq1, r0, c0);
}

// ---- lin0 (MFMA 16x32, fused bn1 on A, 4096 waves): Z0; stats2 ------------
__global__ __launch_bounds__(256) void k_lin0m(const float* T4, const float* sum1,
                                               const float* ssq1, const unsigned short* Wl0b,
                                               float* Z0, float* sum2, float* ssq2) {
  int w = threadIdx.x >> 6;
  int tile = blockIdx.x * 4 + w;                 // 4096 tiles
  int r0 = (tile >> 3) * 16, c0 = (tile & 7) * 32;
  f32x4 acc[2] = {{0,0,0,0},{0,0,0,0}};
  mfma_core_u<128, 2, 1, float>(T4, sum1, ssq1, Wl0b, r0, c0, acc);
  int lane = threadIdx.x & 63, q = lane >> 4, c15 = lane & 15;
#pragma unroll
  for (int nc = 0; nc < 2; ++nc) {
    int cc = c0 + nc * 16 + c15;
    float s = 0.f, s2 = 0.f;
#pragma unroll
    for (int i = 0; i < 4; ++i) {
      int rr = r0 + q * 4 + i;
      float o = acc[nc][i];
      Z0[(size_t)rr * L0_ + cc] = o;
      s += o; s2 += o * o;
    }
    s += __shfl_xor(s, 16, 64); s += __shfl_xor(s, 32, 64);
    s2 += __shfl_xor(s2, 16, 64); s2 += __shfl_xor(s2, 32, 64);
    if (lane < 16) {
      atomicAdd(&sum2[c0 + nc * 16 + lane], s);
      atomicAdd(&ssq2[c0 + nc * 16 + lane], s2);
    }
  }
}

// ---- lin1 (MFMA 16x32, fused elu(bn2) on A, 2048 waves): T6; stats3 -------
__global__ __launch_bounds__(256) void k_lin1m(const float* Z0, const float* sum2,
                                               const float* ssq2, const unsigned short* Wl1b,
                                               const float* T4, const float* sum1,
                                               const float* ssq1,
                                               float* T6, float* sum3, float* ssq3) {
  int w = threadIdx.x >> 6;
  int tile = blockIdx.x * 4 + w;                 // 2048 tiles
  int r0 = (tile >> 2) * 16, c0 = (tile & 3) * 32;
  f32x4 acc[2] = {{0,0,0,0},{0,0,0,0}};
  mfma_core_u<256, 2, 2, float>(Z0, sum2, ssq2, Wl1b, r0, c0, acc);
  int lane = threadIdx.x & 63, q = lane >> 4, c15 = lane & 15;
#pragma unroll
  for (int nc = 0; nc < 2; ++nc) {
    int cc = c0 + nc * 16 + c15;
    float mean = sum1[cc] * (1.f / ROWS);
    float var = ssq1[cc] * (1.f / ROWS) - mean * mean;
    float rs = rsqrtf(var + EPS_);
    float s = 0.f, s2 = 0.f;
#pragma unroll
    for (int i = 0; i < 4; ++i) {
      int rr = r0 + q * 4 + i;
      float o = acc[nc][i] + (T4[(size_t)rr * F_ + cc] - mean) * rs;
      T6[(size_t)rr * F_ + cc] = o;
      s += o; s2 += o * o;
    }
    s += __shfl_xor(s, 16, 64); s += __shfl_xor(s, 32, 64);
    s2 += __shfl_xor(s2, 16, 64); s2 += __shfl_xor(s2, 32, 64);
    if (lane < 16) {
      atomicAdd(&sum3[c0 + nc * 16 + lane], s);
      atomicAdd(&ssq3[c0 + nc * 16 + lane], s2);
    }
  }
}

__global__ void k_norm_out(const float* in, void* out, const float* sum, const float* ssq,
                           const int* flag) {
  int idx = blockIdx.x * 256 + threadIdx.x; int c = idx & (F_ - 1);
  float mean = sum[c] * (1.f / ROWS);
  float var = ssq[c] * (1.f / ROWS) - mean * mean;
  float y = (in[idx] - mean) * rsqrtf(var + EPS_);
  if (*flag) ((float*)out)[idx] = y;
  else       ((__hip_bfloat16*)out)[idx] = __float2bfloat16(y);
}

// ---------------------------------------------------------------------------
extern "C" void kernel_launch(void* const* d_in, const int* in_sizes, int n_in,
                              void* d_out, int out_size, void* d_ws, size_t ws_size,
                              hipStream_t stream) {
  const int* A    = (const int*)d_in[0];
  const void* X   = d_in[1];
  const void* Ws  = d_in[2];
  const void* Wq  = d_in[3];
  const void* Wv  = d_in[4];
  const void* We1 = d_in[5];
  const void* Wl0 = d_in[6];
  const void* Wl1 = d_in[7];

  char* ws = (char*)d_ws;
  size_t off = 0;
  auto alloc = [&](size_t bytes) { size_t o = off; off += (bytes + 255) & ~(size_t)255; return o; };
  size_t o_fill   = alloc(16 * N_ * 4);            // zeroed
  size_t o_stats  = alloc(1024 * 4);               // zeroed
  size_t o_flag   = alloc(256);                    // zeroed
  size_t o_S      = alloc((size_t)64 * G_ * 4);    // zeroed (atomic accum)
  size_t zero_bytes = off;
  size_t o_colbuf = alloc((size_t)16 * N_ * 64 * 4);     // 4 MiB
  size_t o_q      = alloc((size_t)64 * N_ * 4);
  size_t o_v      = alloc((size_t)64 * N_ * 4);
  size_t o_Whb    = alloc((size_t)64 * N_ * G_ * 2);     // 8 MiB bf16
  size_t o_Hcatb  = alloc((size_t)ROWS * C1 * 2);        // 8 MiB bf16
  size_t o_T4     = alloc((size_t)ROWS * F_ * 4);        // f32
  size_t o_T6     = alloc((size_t)ROWS * F_ * 4);
  size_t o_Z0     = alloc((size_t)ROWS * L0_ * 4);       // f32
  size_t o_Wsb    = alloc((size_t)8 * G_ * F_ * 2);
  size_t o_We1b   = alloc((size_t)F_ * C1 * 2);
  size_t o_Wl1b   = alloc((size_t)F_ * L0_ * 2);
  size_t o_Wl0b   = alloc((size_t)L0_ * F_ * 2);

  int*   fill   = (int*)(ws + o_fill);
  float* stats  = (float*)(ws + o_stats);
  int*   flag   = (int*)(ws + o_flag);
  float* S      = (float*)(ws + o_S);
  int*   colbuf = (int*)(ws + o_colbuf);
  float* q      = (float*)(ws + o_q);
  float* v      = (float*)(ws + o_v);
  unsigned short* Whb   = (unsigned short*)(ws + o_Whb);
  unsigned short* Hcatb = (unsigned short*)(ws + o_Hcatb);
  float* T4     = (float*)(ws + o_T4);
  float* T6     = (float*)(ws + o_T6);
  float* Z0     = (float*)(ws + o_Z0);
  unsigned short* Wsb   = (unsigned short*)(ws + o_Wsb);
  unsigned short* We1b  = (unsigned short*)(ws + o_We1b);
  unsigned short* Wl1b  = (unsigned short*)(ws + o_Wl1b);
  unsigned short* Wl0b  = (unsigned short*)(ws + o_Wl0b);
  float* sum1 = stats,       *ssq1 = stats + 128;
  float* sum2 = stats + 256, *ssq2 = stats + 512;
  float* sum3 = stats + 768, *ssq3 = stats + 896;

  hipMemsetAsync(ws, 0, zero_bytes, stream);

  k_prep<<<1536, 256, 0, stream>>>((const unsigned short*)X, flag, A, fill, colbuf);
  k_cvt2<<<768 + 4096, 256, 0, stream>>>(X, Ws, We1, Wl1, Wl0, Wq, Wv,
                                         Wsb, We1b, Wl1b, Wl0b, q, v, flag);
  k_whm<<<dim3(ROWS / 64, 8), 256, 0, stream>>>(X, Wsb, Whb, S, flag);
  k_attn3<<<(16 * N_) / 4, 256, 0, stream>>>(q, v, Whb, S, fill, colbuf, Hcatb);
  k_mm1m<<<512, 256, 0, stream>>>(Hcatb, We1b, X, T4, sum1, ssq1, flag);
  k_lin0m<<<1024, 256, 0, stream>>>(T4, sum1, ssq1, Wl0b, Z0, sum2, ssq2);
  k_lin1m<<<512, 256, 0, stream>>>(Z0, sum2, ssq2, Wl1b, T4, sum1, ssq1,
                                   T6, sum3, ssq3);
  k_norm_out<<<(ROWS * F_) / 256, 256, 0, stream>>>(T6, d_out, sum3, ssq3, flag);

  (void)in_sizes; (void)n_in; (void)out_size; (void)ws_size;
}